// Round 2
// baseline (1184.024 us; speedup 1.0000x reference)
//
#include <hip/hip_runtime.h>
#include <cstdint>
#include <cstddef>

typedef __attribute__((ext_vector_type(8))) short short8;       // 8 x bf16 bits (MFMA A/B frag)
typedef __attribute__((ext_vector_type(4))) float floatx4;      // MFMA C/D frag
typedef __attribute__((ext_vector_type(4))) unsigned int uintx4;
typedef __attribute__((ext_vector_type(4))) unsigned short ushort4x;

#define DEV static __device__ __forceinline__

constexpr int NT = 2, NB = 16, NC = 256, NN = 4096, NHD = 8;
constexpr size_t NE1 = (size_t)NT * NB * NC * NN;   // 33554432 elements per output tensor
constexpr size_t TSTRIDE = (size_t)NB * NC * NN;    // t-stride in elements

// ---------- helpers ----------
DEV unsigned short f2bf(float x) {            // round-to-nearest-even fp32 -> bf16 bits
  unsigned int u = __builtin_bit_cast(unsigned int, x);
  unsigned int lsb = (u >> 16) & 1u;
  u += 0x7FFFu + lsb;
  return (unsigned short)(u >> 16);
}
DEV float bfb2f(unsigned short h) {
  unsigned int u = ((unsigned int)h) << 16;
  return __builtin_bit_cast(float, u);
}
DEV unsigned short spike2bf(float s) {        // s is exactly 0.0f or 1.0f -> truncation exact
  return (unsigned short)(__builtin_bit_cast(unsigned int, s) >> 16);
}
DEV unsigned int pk2(unsigned short a, unsigned short b) {
  return (unsigned int)a | ((unsigned int)b << 16);
}

// ---------- kernel 1: weight split + BN constant prep ----------
__global__ __launch_bounds__(256) void prep_kernel(
    const float* __restrict__ wq, const float* __restrict__ wk, const float* __restrict__ wv,
    const float* __restrict__ wp, const float* __restrict__ bp,
    const float* __restrict__ qg, const float* __restrict__ qb, const float* __restrict__ qm, const float* __restrict__ qva,
    const float* __restrict__ kg, const float* __restrict__ kb, const float* __restrict__ km, const float* __restrict__ kva,
    const float* __restrict__ vg, const float* __restrict__ vb, const float* __restrict__ vm, const float* __restrict__ vva,
    const float* __restrict__ pg, const float* __restrict__ pb, const float* __restrict__ pm, const float* __restrict__ pva,
    unsigned short* __restrict__ Wqkv, unsigned short* __restrict__ Wp,
    float* __restrict__ invqkv, float* __restrict__ shqkv,
    float* __restrict__ invp, float* __restrict__ shp)
{
  int idx = blockIdx.x * 256 + threadIdx.x;
  if (idx < 196608) {                       // Wq|Wk|Wv stacked [768][256], 3-way bf16 split
    int o = idx >> 8, c = idx & 255;
    const float* src = (o < 256) ? wq : (o < 512) ? wk : wv;
    float w = src[(size_t)(o & 255) * 256 + c];
    unsigned short h0 = f2bf(w);  float f0 = bfb2f(h0);
    float r1 = w - f0;
    unsigned short h1 = f2bf(r1); float f1 = bfb2f(h1);
    float r2 = r1 - f1;
    unsigned short h2 = f2bf(r2);
    Wqkv[idx] = h0; Wqkv[196608 + idx] = h1; Wqkv[393216 + idx] = h2;
  } else if (idx < 262144) {                // Wp [256][256], 3-way split
    int j = idx - 196608;
    float w = wp[j];
    unsigned short h0 = f2bf(w);  float f0 = bfb2f(h0);
    float r1 = w - f0;
    unsigned short h1 = f2bf(r1); float f1 = bfb2f(h1);
    float r2 = r1 - f1;
    unsigned short h2 = f2bf(r2);
    Wp[j] = h0; Wp[65536 + j] = h1; Wp[131072 + j] = h2;
  } else if (idx < 262912) {                // BN constants for q,k,v stacked [768]
    int i = idx - 262144;
    int p = i >> 8, c = i & 255;
    float g  = (p == 0) ? qg[c] : (p == 1) ? kg[c] : vg[c];
    float be = (p == 0) ? qb[c] : (p == 1) ? kb[c] : vb[c];
    float mn = (p == 0) ? qm[c] : (p == 1) ? km[c] : vm[c];
    float vr = (p == 0) ? qva[c] : (p == 1) ? kva[c] : vva[c];
    float sq = sqrtf(vr + 1e-5f);
    invqkv[i] = g / sq;
    shqkv[i]  = be - (mn * g) / sq;
  } else if (idx < 263168) {                // BN constants for p, bias folded in
    int c = idx - 262912;
    float sq = sqrtf(pva[c] + 1e-5f);
    float iv = pg[c] / sq;
    invp[c] = iv;
    shp[c]  = pb[c] - (pm[c] * pg[c]) / sq + bp[c] * iv;
  }
}

// ---------- kernel 2: LIF on x -> xs (fp32 [t,b,c,n]) + bf16 transposed [t,b,n,c] ----------
__global__ __launch_bounds__(256) void lifx_kernel(const float* __restrict__ x,
                                                   float* __restrict__ xs_out,
                                                   unsigned short* __restrict__ xs_t)
{
  __shared__ float tile[2][64][65];   // pitch 65 breaks bank aliasing on transpose read
  const int nt = blockIdx.x, ct = blockIdx.y, b = blockIdx.z;
  const int tid = threadIdx.x;
  const int ci = tid >> 2, cq = tid & 3;
  const int n0 = nt * 64, c0 = ct * 64;
  const size_t rowbase = ((size_t)(b * NC + c0 + ci)) * NN + n0 + cq * 16;
  const float* px0 = x + rowbase;
  const float* px1 = x + rowbase + TSTRIDE;
  float* po0 = xs_out + rowbase;
  float* po1 = xs_out + rowbase + TSTRIDE;
  #pragma unroll
  for (int jj = 0; jj < 4; jj++) {
    floatx4 x0 = *(const floatx4*)(px0 + jj * 4);
    floatx4 x1 = *(const floatx4*)(px1 + jj * 4);
    floatx4 s0v, s1v;
    #pragma unroll
    for (int e = 0; e < 4; e++) {
      float v1 = x0[e] * 0.5f;                       // exact
      float s0 = (v1 >= 1.0f) ? 1.0f : 0.0f;
      float vr = v1 * (1.0f - s0);                   // exact (0 or v1)
      float v2 = vr + (x1[e] - vr) * 0.5f;           // same rounding as reference
      float s1 = (v2 >= 1.0f) ? 1.0f : 0.0f;
      s0v[e] = s0; s1v[e] = s1;
      tile[0][ci][cq * 16 + jj * 4 + e] = s0;
      tile[1][ci][cq * 16 + jj * 4 + e] = s1;
    }
    *(floatx4*)(po0 + jj * 4) = s0v;
    *(floatx4*)(po1 + jj * 4) = s1v;
  }
  __syncthreads();
  const int ni = tid >> 2, cg = tid & 3;
  #pragma unroll
  for (int t = 0; t < 2; t++) {
    unsigned short* dst = xs_t + ((size_t)((t * NB + b) * NN) + n0 + ni) * NC + c0 + cg * 16;
    uintx4 w0, w1;
    #pragma unroll
    for (int p2 = 0; p2 < 4; p2++) {
      w0[p2] = pk2(spike2bf(tile[t][cg * 16 + p2 * 2    ][ni]),
                   spike2bf(tile[t][cg * 16 + p2 * 2 + 1][ni]));
      w1[p2] = pk2(spike2bf(tile[t][cg * 16 + p2 * 2 + 8][ni]),
                   spike2bf(tile[t][cg * 16 + p2 * 2 + 9][ni]));
    }
    *(uintx4*)dst = w0;
    *(uintx4*)(dst + 8) = w1;
  }
}

// ---------- kernel 3: fused QKV GEMM (split-3 bf16 MFMA) + BN + LIF -> binary spikes ----------
// Block tile: 128 (out-rows) x 128 (n), both t. 4 waves in 2x2, each 64x64 per t.
__global__ __launch_bounds__(256, 2) void qkv_gemm(
    const unsigned short* __restrict__ xs_t,  // [T][B][N][C] bf16
    const unsigned short* __restrict__ Wsp,   // [3 splits][768][256] bf16
    const float* __restrict__ invv, const float* __restrict__ shv,  // [768]
    float* __restrict__ dq, float* __restrict__ dk, float* __restrict__ dv)
{
  __shared__ __align__(16) unsigned short Al[3][128][40];
  __shared__ __align__(16) unsigned short Bl[2][128][40];
  const int nt = blockIdx.x, mt = blockIdx.y, b = blockIdx.z;
  const int tid = threadIdx.x;
  const int wave = tid >> 6, lane = tid & 63, quad = lane >> 4, l16 = lane & 15;
  const int wm = (wave & 1) * 64, wn = (wave >> 1) * 64;
  floatx4 acc[2][4][4] = {};
  const int srow = tid >> 1, scol = (tid & 1) * 16;
  const unsigned short* wbase  = Wsp + (size_t)(mt * 128 + srow) * 256 + scol;
  const unsigned short* bbase0 = xs_t + ((size_t)(b * NN) + nt * 128 + srow) * NC + scol;
  const unsigned short* bbase1 = xs_t + ((size_t)((NB + b) * NN) + nt * 128 + srow) * NC + scol;

  for (int k0 = 0; k0 < 256; k0 += 32) {
    __syncthreads();
    #pragma unroll
    for (int s = 0; s < 3; s++) {
      const unsigned short* g = wbase + s * 196608 + k0;
      *(uintx4*)&Al[s][srow][scol]     = *(const uintx4*)g;
      *(uintx4*)&Al[s][srow][scol + 8] = *(const uintx4*)(g + 8);
    }
    *(uintx4*)&Bl[0][srow][scol]     = *(const uintx4*)(bbase0 + k0);
    *(uintx4*)&Bl[0][srow][scol + 8] = *(const uintx4*)(bbase0 + k0 + 8);
    *(uintx4*)&Bl[1][srow][scol]     = *(const uintx4*)(bbase1 + k0);
    *(uintx4*)&Bl[1][srow][scol + 8] = *(const uintx4*)(bbase1 + k0 + 8);
    __syncthreads();

    short8 bfr[2][4];
    #pragma unroll
    for (int t = 0; t < 2; t++)
      #pragma unroll
      for (int ni = 0; ni < 4; ni++)
        bfr[t][ni] = *(const short8*)&Bl[t][wn + ni * 16 + l16][quad * 8];
    #pragma unroll
    for (int mi = 0; mi < 4; mi++) {
      short8 a0 = *(const short8*)&Al[0][wm + mi * 16 + l16][quad * 8];
      short8 a1 = *(const short8*)&Al[1][wm + mi * 16 + l16][quad * 8];
      short8 a2 = *(const short8*)&Al[2][wm + mi * 16 + l16][quad * 8];
      #pragma unroll
      for (int t = 0; t < 2; t++)
        #pragma unroll
        for (int ni = 0; ni < 4; ni++) {
          acc[t][mi][ni] = __builtin_amdgcn_mfma_f32_16x16x32_bf16(a0, bfr[t][ni], acc[t][mi][ni], 0, 0, 0);
          acc[t][mi][ni] = __builtin_amdgcn_mfma_f32_16x16x32_bf16(a1, bfr[t][ni], acc[t][mi][ni], 0, 0, 0);
          acc[t][mi][ni] = __builtin_amdgcn_mfma_f32_16x16x32_bf16(a2, bfr[t][ni], acc[t][mi][ni], 0, 0, 0);
        }
    }
  }
  // epilogue: BN + 2-step LIF (v_th = 1.0), write binary spikes fp32
  #pragma unroll
  for (int mi = 0; mi < 4; mi++) {
    #pragma unroll
    for (int r = 0; r < 4; r++) {
      const int orow = mt * 128 + wm + mi * 16 + quad * 4 + r;
      const float iv = invv[orow], sh = shv[orow];
      const int widx = orow >> 8, c = orow & 255;
      float* dst = (widx == 0) ? dq : (widx == 1) ? dk : dv;
      #pragma unroll
      for (int ni = 0; ni < 4; ni++) {
        const int n = nt * 128 + wn + ni * 16 + l16;
        float y0 = acc[0][mi][ni][r] * iv + sh;
        float y1 = acc[1][mi][ni][r] * iv + sh;
        float v1 = y0 * 0.5f;
        float s0 = (v1 >= 1.0f) ? 1.0f : 0.0f;
        float vr = v1 * (1.0f - s0);
        float v2 = vr + (y1 - vr) * 0.5f;
        float s1 = (v2 >= 1.0f) ? 1.0f : 0.0f;
        dst[(size_t)(b * NC + c) * NN + n] = s0;
        dst[(size_t)((NB + b) * NC + c) * NN + n] = s1;
      }
    }
  }
}

// ---------- kernel 4: kv = K^T V per (t,b,h); full in-block reduction, no atomics ----------
__global__ __launch_bounds__(256) void kv_kernel(const float* __restrict__ kspk,
                                                 const float* __restrict__ vspk,
                                                 float* __restrict__ kvout)
{
  __shared__ __align__(16) unsigned short Kl[32][264];  // pitch 264: 132 dwords ≡ 4 mod 32
  __shared__ __align__(16) unsigned short Vl[32][264];
  const int h = blockIdx.x, z = blockIdx.y;             // z = t*16+b
  const int tid = threadIdx.x;
  const int wave = tid >> 6, lane = tid & 63, quad = lane >> 4, l16 = lane & 15;
  const int dh = wave & 1, eh = wave >> 1;
  const size_t base = (size_t)z * NC * NN + (size_t)h * 32 * NN;
  floatx4 acc = {0.f, 0.f, 0.f, 0.f};
  for (int n0 = 0; n0 < NN; n0 += 256) {
    __syncthreads();
    for (int i = tid; i < 2048; i += 256) {             // 32 rows x 64 float4s
      int row = i >> 6, c4 = (i & 63) * 4;
      const size_t g = base + (size_t)row * NN + n0 + c4;
      floatx4 kk = *(const floatx4*)(kspk + g);
      floatx4 vv = *(const floatx4*)(vspk + g);
      ushort4x ks, vs;
      #pragma unroll
      for (int e = 0; e < 4; e++) { ks[e] = spike2bf(kk[e]); vs[e] = spike2bf(vv[e]); }
      *(ushort4x*)&Kl[row][c4] = ks;
      *(ushort4x*)&Vl[row][c4] = vs;
    }
    __syncthreads();
    #pragma unroll
    for (int i = 0; i < 8; i++) {
      short8 ka = *(const short8*)&Kl[dh * 16 + l16][i * 32 + quad * 8];
      short8 vb = *(const short8*)&Vl[eh * 16 + l16][i * 32 + quad * 8];
      acc = __builtin_amdgcn_mfma_f32_16x16x32_bf16(ka, vb, acc, 0, 0, 0);
    }
  }
  float* o = kvout + (size_t)(z * NHD + h) * 1024;
  #pragma unroll
  for (int r = 0; r < 4; r++)
    o[(dh * 16 + quad * 4 + r) * 32 + eh * 16 + l16] = acc[r];
}

// ---------- kernel 5: attn = 0.125*(q@kv) (exact), LIF(v_th=0.5) -> s spikes bf16 [t,b,n,c] ----------
__global__ __launch_bounds__(256) void attn_kernel(const float* __restrict__ qspk,
                                                   const float* __restrict__ kv,
                                                   unsigned short* __restrict__ s_t)
{
  __shared__ float kvl[2][32][32];
  const int nb = blockIdx.x, h = blockIdx.y, b = blockIdx.z;
  const int tid = threadIdx.x;
  for (int i = tid; i < 2048; i += 256) {
    int t = i >> 10, j = i & 1023;
    kvl[t][j >> 5][j & 31] = kv[((size_t)((t * NB + b) * NHD + h) << 10) + j];
  }
  __syncthreads();
  const int n = nb * 256 + tid;
  float X[2][32];
  #pragma unroll
  for (int t = 0; t < 2; t++) {
    #pragma unroll
    for (int e = 0; e < 32; e++) X[t][e] = 0.f;
    const float* qp = qspk + ((size_t)((t * NB + b) * NC + h * 32)) * NN + n;
    #pragma unroll 4
    for (int d = 0; d < 32; d++) {
      float qv = qp[(size_t)d * NN];
      #pragma unroll
      for (int e = 0; e < 32; e++) X[t][e] += qv * kvl[t][d][e];  // LDS broadcast
    }
  }
  unsigned short o0[32], o1[32];
  #pragma unroll
  for (int e = 0; e < 32; e++) {
    float a0 = X[0][e] * 0.125f;                 // exact dyadic arithmetic throughout
    float a1 = X[1][e] * 0.125f;
    float v1 = a0 * 0.5f;
    float s0 = (v1 >= 0.5f) ? 1.f : 0.f;
    float vr = v1 * (1.f - s0);
    float v2 = vr + (a1 - vr) * 0.5f;
    float s1 = (v2 >= 0.5f) ? 1.f : 0.f;
    o0[e] = s0 != 0.f ? (unsigned short)0x3F80 : (unsigned short)0;
    o1[e] = s1 != 0.f ? (unsigned short)0x3F80 : (unsigned short)0;
  }
  unsigned short* dst0 = s_t + ((size_t)(b * NN) + n) * NC + h * 32;
  unsigned short* dst1 = s_t + ((size_t)((NB + b) * NN) + n) * NC + h * 32;
  #pragma unroll
  for (int g = 0; g < 4; g++) {
    uintx4 w0, w1;
    #pragma unroll
    for (int p = 0; p < 4; p++) {
      w0[p] = pk2(o0[g * 8 + p * 2], o0[g * 8 + p * 2 + 1]);
      w1[p] = pk2(o1[g * 8 + p * 2], o1[g * 8 + p * 2 + 1]);
    }
    *(uintx4*)(dst0 + g * 8) = w0;
    *(uintx4*)(dst1 + g * 8) = w1;
  }
}

// ---------- kernel 6: out = BN(Wp @ s + bp) (split-3 bf16 MFMA, bias folded in shift) ----------
__global__ __launch_bounds__(256, 2) void p_gemm(
    const unsigned short* __restrict__ s_t,   // [T][B][N][C] bf16
    const unsigned short* __restrict__ Wsp,   // [3][256][256]
    const float* __restrict__ invv, const float* __restrict__ shv,
    float* __restrict__ dout)
{
  __shared__ __align__(16) unsigned short Al[3][128][40];
  __shared__ __align__(16) unsigned short Bl[128][40];
  const int nt = blockIdx.x, mt = blockIdx.y, z = blockIdx.z;  // z = t*16+b
  const int tid = threadIdx.x;
  const int wave = tid >> 6, lane = tid & 63, quad = lane >> 4, l16 = lane & 15;
  const int wm = (wave & 1) * 64, wn = (wave >> 1) * 64;
  floatx4 acc[4][4] = {};
  const int srow = tid >> 1, scol = (tid & 1) * 16;
  const unsigned short* wbase = Wsp + (size_t)(mt * 128 + srow) * 256 + scol;
  const unsigned short* bbase = s_t + ((size_t)(z * NN) + nt * 128 + srow) * NC + scol;

  for (int k0 = 0; k0 < 256; k0 += 32) {
    __syncthreads();
    #pragma unroll
    for (int s = 0; s < 3; s++) {
      const unsigned short* g = wbase + s * 65536 + k0;
      *(uintx4*)&Al[s][srow][scol]     = *(const uintx4*)g;
      *(uintx4*)&Al[s][srow][scol + 8] = *(const uintx4*)(g + 8);
    }
    *(uintx4*)&Bl[srow][scol]     = *(const uintx4*)(bbase + k0);
    *(uintx4*)&Bl[srow][scol + 8] = *(const uintx4*)(bbase + k0 + 8);
    __syncthreads();

    short8 bfr[4];
    #pragma unroll
    for (int ni = 0; ni < 4; ni++)
      bfr[ni] = *(const short8*)&Bl[wn + ni * 16 + l16][quad * 8];
    #pragma unroll
    for (int mi = 0; mi < 4; mi++) {
      short8 a0 = *(const short8*)&Al[0][wm + mi * 16 + l16][quad * 8];
      short8 a1 = *(const short8*)&Al[1][wm + mi * 16 + l16][quad * 8];
      short8 a2 = *(const short8*)&Al[2][wm + mi * 16 + l16][quad * 8];
      #pragma unroll
      for (int ni = 0; ni < 4; ni++) {
        acc[mi][ni] = __builtin_amdgcn_mfma_f32_16x16x32_bf16(a0, bfr[ni], acc[mi][ni], 0, 0, 0);
        acc[mi][ni] = __builtin_amdgcn_mfma_f32_16x16x32_bf16(a1, bfr[ni], acc[mi][ni], 0, 0, 0);
        acc[mi][ni] = __builtin_amdgcn_mfma_f32_16x16x32_bf16(a2, bfr[ni], acc[mi][ni], 0, 0, 0);
      }
    }
  }
  #pragma unroll
  for (int mi = 0; mi < 4; mi++) {
    #pragma unroll
    for (int r = 0; r < 4; r++) {
      const int orow = mt * 128 + wm + mi * 16 + quad * 4 + r;
      const float iv = invv[orow], sh = shv[orow];
      #pragma unroll
      for (int ni = 0; ni < 4; ni++) {
        const int n = nt * 128 + wn + ni * 16 + l16;
        dout[((size_t)(z * NC + orow)) * NN + n] = acc[mi][ni][r] * iv + sh;
      }
    }
  }
}

// ---------- launch ----------
extern "C" void kernel_launch(void* const* d_in, const int* in_sizes, int n_in,
                              void* d_out, int out_size, void* d_ws, size_t ws_size,
                              hipStream_t stream) {
  (void)in_sizes; (void)n_in; (void)out_size; (void)ws_size;
  const float* x  = (const float*)d_in[0];
  const float* wq = (const float*)d_in[1];
  const float* wk = (const float*)d_in[2];
  const float* wv = (const float*)d_in[3];
  const float* wp = (const float*)d_in[4];
  const float* bp = (const float*)d_in[5];
  const float* qg = (const float*)d_in[6],  *qb = (const float*)d_in[7];
  const float* qm = (const float*)d_in[8],  *qva = (const float*)d_in[9];
  const float* kg = (const float*)d_in[10], *kb = (const float*)d_in[11];
  const float* km = (const float*)d_in[12], *kva = (const float*)d_in[13];
  const float* vg = (const float*)d_in[14], *vb = (const float*)d_in[15];
  const float* vm = (const float*)d_in[16], *vva = (const float*)d_in[17];
  const float* pg = (const float*)d_in[18], *pb = (const float*)d_in[19];
  const float* pm = (const float*)d_in[20], *pva = (const float*)d_in[21];

  float* out = (float*)d_out;       // outputs in return order
  float* xs  = out + NE1;
  float* dq  = out + 2 * NE1;
  float* dk  = out + 3 * NE1;
  float* dv  = out + 4 * NE1;

  // workspace layout (66.5 MiB total); s_t aliases xs_t (sequentially safe:
  // xs_t last read by qkv_gemm, s_t first written by attn_kernel two dispatches later)
  char* ws = (char*)d_ws;
  unsigned short* xs_t = (unsigned short*)ws;                   // 67108864 B
  unsigned short* s_t  = (unsigned short*)ws;                   // aliases xs_t
  unsigned short* Wqkv = (unsigned short*)(ws + 67108864);      // 1179648 B
  unsigned short* Wp   = (unsigned short*)(ws + 68288512);      // 393216 B
  float* kvb           = (float*)(ws + 68681728);               // 1048576 B
  float* invqkv        = (float*)(ws + 69730304);               // 768 floats
  float* shqkv         = invqkv + 768;
  float* invp          = shqkv + 768;
  float* shp           = invp + 256;

  prep_kernel<<<1028, 256, 0, stream>>>(wq, wk, wv, wp, bp,
                                        qg, qb, qm, qva, kg, kb, km, kva,
                                        vg, vb, vm, vva, pg, pb, pm, pva,
                                        Wqkv, Wp, invqkv, shqkv, invp, shp);
  lifx_kernel<<<dim3(64, 4, 16), 256, 0, stream>>>(x, xs, xs_t);
  qkv_gemm<<<dim3(32, 6, 16), 256, 0, stream>>>(xs_t, Wqkv, invqkv, shqkv, dq, dk, dv);
  kv_kernel<<<dim3(8, 32), 256, 0, stream>>>(dk, dv, kvb);
  attn_kernel<<<dim3(16, 8, 16), 256, 0, stream>>>(dq, kvb, s_t);
  p_gemm<<<dim3(32, 2, 32), 256, 0, stream>>>(s_t, Wp, invp, shp, out);
}

// Round 3
// 1128.035 us; speedup vs baseline: 1.0496x; 1.0496x over previous
//
#include <hip/hip_runtime.h>
#include <cstdint>
#include <cstddef>

typedef __attribute__((ext_vector_type(8))) short short8;       // 8 x bf16 bits (MFMA A/B frag)
typedef __attribute__((ext_vector_type(4))) float floatx4;      // MFMA C/D frag
typedef __attribute__((ext_vector_type(4))) unsigned int uintx4;
typedef __attribute__((ext_vector_type(4))) unsigned short ushort4x;

#define DEV static __device__ __forceinline__

constexpr int NT = 2, NB = 16, NC = 256, NN = 4096, NHD = 8;
constexpr size_t NE1 = (size_t)NT * NB * NC * NN;   // 33554432 elements per output tensor
constexpr size_t TSTRIDE = (size_t)NB * NC * NN;    // t-stride in elements

// ---------- helpers ----------
DEV unsigned short f2bf(float x) {            // round-to-nearest-even fp32 -> bf16 bits
  unsigned int u = __builtin_bit_cast(unsigned int, x);
  unsigned int lsb = (u >> 16) & 1u;
  u += 0x7FFFu + lsb;
  return (unsigned short)(u >> 16);
}
DEV float bfb2f(unsigned short h) {
  unsigned int u = ((unsigned int)h) << 16;
  return __builtin_bit_cast(float, u);
}
DEV unsigned short spike2bf(float s) {        // s is exactly 0.0f or 1.0f -> truncation exact
  return (unsigned short)(__builtin_bit_cast(unsigned int, s) >> 16);
}
DEV unsigned int pk2(unsigned short a, unsigned short b) {
  return (unsigned int)a | ((unsigned int)b << 16);
}
// async global->LDS, 16B per lane; LDS dest must be wave-uniform base + lane*16
typedef __attribute__((address_space(3))) unsigned int lds_u32;
typedef __attribute__((address_space(1))) const unsigned int glb_u32;
DEV void gld_lds16(const void* g, void* l) {
  __builtin_amdgcn_global_load_lds((glb_u32*)g, (lds_u32*)l, 16, 0, 0);
}

// ---------- kernel 1: weight split + BN constant prep ----------
__global__ __launch_bounds__(256) void prep_kernel(
    const float* __restrict__ wq, const float* __restrict__ wk, const float* __restrict__ wv,
    const float* __restrict__ wp, const float* __restrict__ bp,
    const float* __restrict__ qg, const float* __restrict__ qb, const float* __restrict__ qm, const float* __restrict__ qva,
    const float* __restrict__ kg, const float* __restrict__ kb, const float* __restrict__ km, const float* __restrict__ kva,
    const float* __restrict__ vg, const float* __restrict__ vb, const float* __restrict__ vm, const float* __restrict__ vva,
    const float* __restrict__ pg, const float* __restrict__ pb, const float* __restrict__ pm, const float* __restrict__ pva,
    unsigned short* __restrict__ Wqkv, unsigned short* __restrict__ Wp,
    float* __restrict__ invqkv, float* __restrict__ shqkv,
    float* __restrict__ invp, float* __restrict__ shp)
{
  int idx = blockIdx.x * 256 + threadIdx.x;
  if (idx < 196608) {                       // Wq|Wk|Wv stacked [768][256], 3-way bf16 split
    int o = idx >> 8, c = idx & 255;
    const float* src = (o < 256) ? wq : (o < 512) ? wk : wv;
    float w = src[(size_t)(o & 255) * 256 + c];
    unsigned short h0 = f2bf(w);  float f0 = bfb2f(h0);
    float r1 = w - f0;
    unsigned short h1 = f2bf(r1); float f1 = bfb2f(h1);
    float r2 = r1 - f1;
    unsigned short h2 = f2bf(r2);
    Wqkv[idx] = h0; Wqkv[196608 + idx] = h1; Wqkv[393216 + idx] = h2;
  } else if (idx < 262144) {                // Wp [256][256], 3-way split
    int j = idx - 196608;
    float w = wp[j];
    unsigned short h0 = f2bf(w);  float f0 = bfb2f(h0);
    float r1 = w - f0;
    unsigned short h1 = f2bf(r1); float f1 = bfb2f(h1);
    float r2 = r1 - f1;
    unsigned short h2 = f2bf(r2);
    Wp[j] = h0; Wp[65536 + j] = h1; Wp[131072 + j] = h2;
  } else if (idx < 262912) {                // BN constants for q,k,v stacked [768]
    int i = idx - 262144;
    int p = i >> 8, c = i & 255;
    float g  = (p == 0) ? qg[c] : (p == 1) ? kg[c] : vg[c];
    float be = (p == 0) ? qb[c] : (p == 1) ? kb[c] : vb[c];
    float mn = (p == 0) ? qm[c] : (p == 1) ? km[c] : vm[c];
    float vr = (p == 0) ? qva[c] : (p == 1) ? kva[c] : vva[c];
    float sq = sqrtf(vr + 1e-5f);
    invqkv[i] = g / sq;
    shqkv[i]  = be - (mn * g) / sq;
  } else if (idx < 263168) {                // BN constants for p, bias folded in
    int c = idx - 262912;
    float sq = sqrtf(pva[c] + 1e-5f);
    float iv = pg[c] / sq;
    invp[c] = iv;
    shp[c]  = pb[c] - (pm[c] * pg[c]) / sq + bp[c] * iv;
  }
}

// ---------- kernel 2: LIF on x -> xs (fp32 [t,b,c,n]) + bf16 transposed [t,b,n,c] ----------
__global__ __launch_bounds__(256) void lifx_kernel(const float* __restrict__ x,
                                                   float* __restrict__ xs_out,
                                                   unsigned short* __restrict__ xs_t)
{
  __shared__ float tile[2][64][65];
  const int nt = blockIdx.x, ct = blockIdx.y, b = blockIdx.z;
  const int tid = threadIdx.x;
  const int ci = tid >> 2, cq = tid & 3;
  const int n0 = nt * 64, c0 = ct * 64;
  const size_t rowbase = ((size_t)(b * NC + c0 + ci)) * NN + n0 + cq * 16;
  const float* px0 = x + rowbase;
  const float* px1 = x + rowbase + TSTRIDE;
  float* po0 = xs_out + rowbase;
  float* po1 = xs_out + rowbase + TSTRIDE;
  #pragma unroll
  for (int jj = 0; jj < 4; jj++) {
    floatx4 x0 = *(const floatx4*)(px0 + jj * 4);
    floatx4 x1 = *(const floatx4*)(px1 + jj * 4);
    floatx4 s0v, s1v;
    #pragma unroll
    for (int e = 0; e < 4; e++) {
      float v1 = x0[e] * 0.5f;                       // exact
      float s0 = (v1 >= 1.0f) ? 1.0f : 0.0f;
      float vr = v1 * (1.0f - s0);                   // exact (0 or v1)
      float v2 = vr + (x1[e] - vr) * 0.5f;           // same rounding as reference
      float s1 = (v2 >= 1.0f) ? 1.0f : 0.0f;
      s0v[e] = s0; s1v[e] = s1;
      tile[0][ci][cq * 16 + jj * 4 + e] = s0;
      tile[1][ci][cq * 16 + jj * 4 + e] = s1;
    }
    *(floatx4*)(po0 + jj * 4) = s0v;
    *(floatx4*)(po1 + jj * 4) = s1v;
  }
  __syncthreads();
  const int ni = tid >> 2, cg = tid & 3;
  #pragma unroll
  for (int t = 0; t < 2; t++) {
    unsigned short* dst = xs_t + ((size_t)((t * NB + b) * NN) + n0 + ni) * NC + c0 + cg * 16;
    uintx4 w0, w1;
    #pragma unroll
    for (int p2 = 0; p2 < 4; p2++) {
      w0[p2] = pk2(spike2bf(tile[t][cg * 16 + p2 * 2    ][ni]),
                   spike2bf(tile[t][cg * 16 + p2 * 2 + 1][ni]));
      w1[p2] = pk2(spike2bf(tile[t][cg * 16 + p2 * 2 + 8][ni]),
                   spike2bf(tile[t][cg * 16 + p2 * 2 + 9][ni]));
    }
    *(uintx4*)dst = w0;
    *(uintx4*)(dst + 8) = w1;
  }
}

// ---------- kernel 3: fused QKV GEMM + BN + LIF ----------
// Block: M=128 x N=64 x T=2. Wave = (t, M-half): acc 64 VGPR/wave -> 3 blocks/CU.
// All staging via global_load_lds(16). t0<->t1 coupling resolved by LDS exchange.
__global__ __launch_bounds__(256, 3) void qkv_gemm(
    const unsigned short* __restrict__ xs_t,  // [T][B][N][C] bf16
    const unsigned short* __restrict__ Wsp,   // [3 splits][768][256] bf16
    const float* __restrict__ invv, const float* __restrict__ shv,  // [768]
    float* __restrict__ dq, float* __restrict__ dk, float* __restrict__ dv)
{
  __shared__ __align__(16) unsigned char smem[33280];
  unsigned short* Al = (unsigned short*)smem;            // [3][128][32] = 24576 B (unpadded)
  unsigned short* Bl = (unsigned short*)(smem + 24576);  // [2][64][32]  =  8192 B (unpadded)
  float* yl = (float*)smem;                              // [128][65] overlaid for exchange
  const int nt = blockIdx.x, mt = blockIdx.y, b = blockIdx.z;
  const int tid = threadIdx.x;
  const int lane = tid & 63, quad = lane >> 4, l16 = lane & 15;
  const int wave = tid >> 6;
  const int tw = wave >> 1, wm = (wave & 1) * 64;        // waves 0,1: t=0 ; waves 2,3: t=1
  floatx4 acc[4][4] = {};

  for (int k0 = 0; k0 < 256; k0 += 32) {
    __syncthreads();
    #pragma unroll
    for (int j = 0; j < 6; j++) {            // A: 3 splits x 128 rows x 32k
      int ci = j * 256 + tid;
      int s = ci >> 9, j2 = ci & 511, row = j2 >> 2, kk = j2 & 3;
      const unsigned short* g = Wsp + (size_t)s * 196608 + (size_t)(mt * 128 + row) * 256 + k0 + kk * 8;
      gld_lds16(g, Al + ci * 8);
    }
    #pragma unroll
    for (int j = 0; j < 2; j++) {            // B: 2t x 64 rows x 32k
      int ci = j * 256 + tid;
      int t = ci >> 8, j2 = ci & 255, row = j2 >> 2, kk = j2 & 3;
      const unsigned short* g = xs_t + ((size_t)((t * NB + b) * NN) + nt * 64 + row) * NC + k0 + kk * 8;
      gld_lds16(g, Bl + ci * 8);
    }
    __syncthreads();

    short8 bfr[4];
    #pragma unroll
    for (int ni = 0; ni < 4; ni++)
      bfr[ni] = *(const short8*)(Bl + ((size_t)(tw * 64 + ni * 16 + l16)) * 32 + quad * 8);
    #pragma unroll
    for (int mi = 0; mi < 4; mi++) {
      const int arow = wm + mi * 16 + l16;
      short8 a0 = *(const short8*)(Al + ((size_t)(          arow)) * 32 + quad * 8);
      short8 a1 = *(const short8*)(Al + ((size_t)(128  +   arow)) * 32 + quad * 8);
      short8 a2 = *(const short8*)(Al + ((size_t)(256  +   arow)) * 32 + quad * 8);
      #pragma unroll
      for (int ni = 0; ni < 4; ni++) {
        acc[mi][ni] = __builtin_amdgcn_mfma_f32_16x16x32_bf16(a0, bfr[ni], acc[mi][ni], 0, 0, 0);
        acc[mi][ni] = __builtin_amdgcn_mfma_f32_16x16x32_bf16(a1, bfr[ni], acc[mi][ni], 0, 0, 0);
        acc[mi][ni] = __builtin_amdgcn_mfma_f32_16x16x32_bf16(a2, bfr[ni], acc[mi][ni], 0, 0, 0);
      }
    }
  }
  __syncthreads();                 // staging LDS now dead; reuse as exchange
  if (tw == 0) {                   // t0 waves publish raw accumulators
    #pragma unroll
    for (int mi = 0; mi < 4; mi++)
      #pragma unroll
      for (int r = 0; r < 4; r++)
        #pragma unroll
        for (int ni = 0; ni < 4; ni++)
          yl[(size_t)(wm + mi * 16 + quad * 4 + r) * 65 + ni * 16 + l16] = acc[mi][ni][r];
  }
  __syncthreads();
  if (tw == 1) {                   // t1 waves apply BN + 2-step LIF, write both planes
    #pragma unroll
    for (int mi = 0; mi < 4; mi++) {
      #pragma unroll
      for (int r = 0; r < 4; r++) {
        const int lrow = wm + mi * 16 + quad * 4 + r;
        const int orow = mt * 128 + lrow;
        const float iv = invv[orow], sh = shv[orow];
        const int widx = orow >> 8, c = orow & 255;
        float* dst = (widx == 0) ? dq : (widx == 1) ? dk : dv;
        #pragma unroll
        for (int ni = 0; ni < 4; ni++) {
          const int n = nt * 64 + ni * 16 + l16;
          float y0 = yl[(size_t)lrow * 65 + ni * 16 + l16] * iv + sh;
          float y1 = acc[mi][ni][r] * iv + sh;
          float v1 = y0 * 0.5f;
          float s0 = (v1 >= 1.0f) ? 1.0f : 0.0f;
          float vr = v1 * (1.0f - s0);
          float v2 = vr + (y1 - vr) * 0.5f;
          float s1 = (v2 >= 1.0f) ? 1.0f : 0.0f;
          dst[(size_t)(b * NC + c) * NN + n] = s0;
          dst[(size_t)((NB + b) * NC + c) * NN + n] = s1;
        }
      }
    }
  }
}

// ---------- kernel 4: kv partials = K^T V over an N-chunk of 1024; exact integer partials ----------
__global__ __launch_bounds__(256) void kv_kernel(const float* __restrict__ kspk,
                                                 const float* __restrict__ vspk,
                                                 float* __restrict__ kvp)
{
  __shared__ __align__(16) unsigned short Kl[32][264];
  __shared__ __align__(16) unsigned short Vl[32][264];
  const int h = blockIdx.x, z = blockIdx.y, ch = blockIdx.z;   // z = t*16+b, ch = N chunk
  const int tid = threadIdx.x;
  const int wave = tid >> 6, lane = tid & 63, quad = lane >> 4, l16 = lane & 15;
  const int dh = wave & 1, eh = wave >> 1;
  const size_t base = (size_t)z * NC * NN + (size_t)h * 32 * NN + (size_t)ch * 1024;
  floatx4 acc = {0.f, 0.f, 0.f, 0.f};
  for (int n0 = 0; n0 < 1024; n0 += 256) {
    __syncthreads();
    for (int i = tid; i < 2048; i += 256) {             // 32 rows x 64 float4s
      int row = i >> 6, c4 = (i & 63) * 4;
      const size_t g = base + (size_t)row * NN + n0 + c4;
      floatx4 kk = *(const floatx4*)(kspk + g);
      floatx4 vv = *(const floatx4*)(vspk + g);
      ushort4x ks, vs;
      #pragma unroll
      for (int e = 0; e < 4; e++) { ks[e] = spike2bf(kk[e]); vs[e] = spike2bf(vv[e]); }
      *(ushort4x*)&Kl[row][c4] = ks;
      *(ushort4x*)&Vl[row][c4] = vs;
    }
    __syncthreads();
    #pragma unroll
    for (int i = 0; i < 8; i++) {
      short8 ka = *(const short8*)&Kl[dh * 16 + l16][i * 32 + quad * 8];
      short8 vb = *(const short8*)&Vl[eh * 16 + l16][i * 32 + quad * 8];
      acc = __builtin_amdgcn_mfma_f32_16x16x32_bf16(ka, vb, acc, 0, 0, 0);
    }
  }
  float* o = kvp + ((size_t)((ch * 32 + z) * NHD + h)) * 1024;
  #pragma unroll
  for (int r = 0; r < 4; r++)
    o[(dh * 16 + quad * 4 + r) * 32 + eh * 16 + l16] = acc[r];
}

// ---------- kernel 5: attn = 0.125*(q@kv) (exact), LIF(0.5) -> s spikes bf16 [t,b,n,c] ----------
__global__ __launch_bounds__(256) void attn_kernel(const float* __restrict__ qspk,
                                                   const float* __restrict__ kvp,
                                                   unsigned short* __restrict__ s_t)
{
  __shared__ float kvl[2][32][32];
  const int nb = blockIdx.x, h = blockIdx.y, b = blockIdx.z;
  const int tid = threadIdx.x;
  for (int i = tid; i < 2048; i += 256) {     // sum 4 exact-integer partials
    int t = i >> 10, j = i & 1023;
    size_t o = ((size_t)((t * NB + b) * NHD + h) << 10) + j;
    float v = kvp[o] + kvp[o + 262144] + kvp[o + 524288] + kvp[o + 786432];
    kvl[t][j >> 5][j & 31] = v;
  }
  __syncthreads();
  const int n = nb * 256 + tid;
  float X[2][32];
  #pragma unroll
  for (int t = 0; t < 2; t++) {
    #pragma unroll
    for (int e = 0; e < 32; e++) X[t][e] = 0.f;
    const float* qp = qspk + ((size_t)((t * NB + b) * NC + h * 32)) * NN + n;
    #pragma unroll 4
    for (int d = 0; d < 32; d++) {
      float qv = qp[(size_t)d * NN];
      #pragma unroll
      for (int e = 0; e < 32; e++) X[t][e] += qv * kvl[t][d][e];  // LDS broadcast
    }
  }
  unsigned short o0[32], o1[32];
  #pragma unroll
  for (int e = 0; e < 32; e++) {
    float a0 = X[0][e] * 0.125f;                 // exact dyadic arithmetic throughout
    float a1 = X[1][e] * 0.125f;
    float v1 = a0 * 0.5f;
    float s0 = (v1 >= 0.5f) ? 1.f : 0.f;
    float vr = v1 * (1.f - s0);
    float v2 = vr + (a1 - vr) * 0.5f;
    float s1 = (v2 >= 0.5f) ? 1.f : 0.f;
    o0[e] = s0 != 0.f ? (unsigned short)0x3F80 : (unsigned short)0;
    o1[e] = s1 != 0.f ? (unsigned short)0x3F80 : (unsigned short)0;
  }
  unsigned short* dst0 = s_t + ((size_t)(b * NN) + n) * NC + h * 32;
  unsigned short* dst1 = s_t + ((size_t)((NB + b) * NN) + n) * NC + h * 32;
  #pragma unroll
  for (int g = 0; g < 4; g++) {
    uintx4 w0, w1;
    #pragma unroll
    for (int p = 0; p < 4; p++) {
      w0[p] = pk2(o0[g * 8 + p * 2], o0[g * 8 + p * 2 + 1]);
      w1[p] = pk2(o1[g * 8 + p * 2], o1[g * 8 + p * 2 + 1]);
    }
    *(uintx4*)(dst0 + g * 8) = w0;
    *(uintx4*)(dst1 + g * 8) = w1;
  }
}

// ---------- kernel 6: out = BN(Wp @ s + bp) ----------
__global__ __launch_bounds__(256, 3) void p_gemm(
    const unsigned short* __restrict__ s_t,   // [T][B][N][C] bf16
    const unsigned short* __restrict__ Wsp,   // [3][256][256]
    const float* __restrict__ invv, const float* __restrict__ shv,
    float* __restrict__ dout)
{
  __shared__ __align__(16) unsigned char smem[32768];
  unsigned short* Al = (unsigned short*)smem;            // [3][128][32] = 24576 B
  unsigned short* Bl = (unsigned short*)(smem + 24576);  // [128][32]    =  8192 B
  const int nt = blockIdx.x, mt = blockIdx.y, z = blockIdx.z;  // z = t*16+b
  const int tid = threadIdx.x;
  const int lane = tid & 63, quad = lane >> 4, l16 = lane & 15;
  const int wave = tid >> 6;
  const int wm = (wave & 1) * 64, wn = (wave >> 1) * 64;
  floatx4 acc[4][4] = {};

  for (int k0 = 0; k0 < 256; k0 += 32) {
    __syncthreads();
    #pragma unroll
    for (int j = 0; j < 6; j++) {
      int ci = j * 256 + tid;
      int s = ci >> 9, j2 = ci & 511, row = j2 >> 2, kk = j2 & 3;
      const unsigned short* g = Wsp + (size_t)s * 65536 + (size_t)(mt * 128 + row) * 256 + k0 + kk * 8;
      gld_lds16(g, Al + ci * 8);
    }
    #pragma unroll
    for (int j = 0; j < 2; j++) {
      int ci = j * 256 + tid;
      int row = ci >> 2, kk = ci & 3;
      const unsigned short* g = s_t + ((size_t)(z * NN) + nt * 128 + row) * NC + k0 + kk * 8;
      gld_lds16(g, Bl + ci * 8);
    }
    __syncthreads();

    short8 bfr[4];
    #pragma unroll
    for (int ni = 0; ni < 4; ni++)
      bfr[ni] = *(const short8*)(Bl + ((size_t)(wn + ni * 16 + l16)) * 32 + quad * 8);
    #pragma unroll
    for (int mi = 0; mi < 4; mi++) {
      const int arow = wm + mi * 16 + l16;
      short8 a0 = *(const short8*)(Al + ((size_t)(        arow)) * 32 + quad * 8);
      short8 a1 = *(const short8*)(Al + ((size_t)(128 +   arow)) * 32 + quad * 8);
      short8 a2 = *(const short8*)(Al + ((size_t)(256 +   arow)) * 32 + quad * 8);
      #pragma unroll
      for (int ni = 0; ni < 4; ni++) {
        acc[mi][ni] = __builtin_amdgcn_mfma_f32_16x16x32_bf16(a0, bfr[ni], acc[mi][ni], 0, 0, 0);
        acc[mi][ni] = __builtin_amdgcn_mfma_f32_16x16x32_bf16(a1, bfr[ni], acc[mi][ni], 0, 0, 0);
        acc[mi][ni] = __builtin_amdgcn_mfma_f32_16x16x32_bf16(a2, bfr[ni], acc[mi][ni], 0, 0, 0);
      }
    }
  }
  #pragma unroll
  for (int mi = 0; mi < 4; mi++) {
    #pragma unroll
    for (int r = 0; r < 4; r++) {
      const int orow = mt * 128 + wm + mi * 16 + quad * 4 + r;
      const float iv = invv[orow], sh = shv[orow];
      #pragma unroll
      for (int ni = 0; ni < 4; ni++) {
        const int n = nt * 128 + wn + ni * 16 + l16;
        dout[((size_t)(z * NC + orow)) * NN + n] = acc[mi][ni][r] * iv + sh;
      }
    }
  }
}

// ---------- launch ----------
extern "C" void kernel_launch(void* const* d_in, const int* in_sizes, int n_in,
                              void* d_out, int out_size, void* d_ws, size_t ws_size,
                              hipStream_t stream) {
  (void)in_sizes; (void)n_in; (void)out_size; (void)ws_size;
  const float* x  = (const float*)d_in[0];
  const float* wq = (const float*)d_in[1];
  const float* wk = (const float*)d_in[2];
  const float* wv = (const float*)d_in[3];
  const float* wp = (const float*)d_in[4];
  const float* bp = (const float*)d_in[5];
  const float* qg = (const float*)d_in[6],  *qb = (const float*)d_in[7];
  const float* qm = (const float*)d_in[8],  *qva = (const float*)d_in[9];
  const float* kg = (const float*)d_in[10], *kb = (const float*)d_in[11];
  const float* km = (const float*)d_in[12], *kva = (const float*)d_in[13];
  const float* vg = (const float*)d_in[14], *vb = (const float*)d_in[15];
  const float* vm = (const float*)d_in[16], *vva = (const float*)d_in[17];
  const float* pg = (const float*)d_in[18], *pb = (const float*)d_in[19];
  const float* pm = (const float*)d_in[20], *pva = (const float*)d_in[21];

  float* out = (float*)d_out;       // outputs in return order
  float* xs  = out + NE1;
  float* dq  = out + 2 * NE1;
  float* dk  = out + 3 * NE1;
  float* dv  = out + 4 * NE1;

  // workspace layout; s_t aliases xs_t (xs_t last read by qkv_gemm,
  // s_t first written by attn_kernel two dispatches later)
  char* ws = (char*)d_ws;
  unsigned short* xs_t = (unsigned short*)ws;                   // 67108864 B
  unsigned short* s_t  = (unsigned short*)ws;                   // aliases xs_t
  unsigned short* Wqkv = (unsigned short*)(ws + 67108864);      // 1179648 B
  unsigned short* Wp   = (unsigned short*)(ws + 68288512);      // 393216 B
  float* kvp           = (float*)(ws + 68681728);               // 4194304 B (4 partials)
  float* invqkv        = (float*)(ws + 72876032);               // 768 floats
  float* shqkv         = invqkv + 768;
  float* invp          = shqkv + 768;
  float* shp           = invp + 256;

  prep_kernel<<<1028, 256, 0, stream>>>(wq, wk, wv, wp, bp,
                                        qg, qb, qm, qva, kg, kb, km, kva,
                                        vg, vb, vm, vva, pg, pb, pm, pva,
                                        Wqkv, Wp, invqkv, shqkv, invp, shp);
  lifx_kernel<<<dim3(64, 4, 16), 256, 0, stream>>>(x, xs, xs_t);
  qkv_gemm<<<dim3(64, 6, 16), 256, 0, stream>>>(xs_t, Wqkv, invqkv, shqkv, dq, dk, dv);
  kv_kernel<<<dim3(8, 32, 4), 256, 0, stream>>>(dk, dv, kvp);
  attn_kernel<<<dim3(16, 8, 16), 256, 0, stream>>>(dq, kvp, s_t);
  p_gemm<<<dim3(32, 2, 32), 256, 0, stream>>>(s_t, Wp, invp, shp, out);
}

// Round 4
// 1092.543 us; speedup vs baseline: 1.0837x; 1.0325x over previous
//
#include <hip/hip_runtime.h>
#include <cstdint>
#include <cstddef>

typedef __attribute__((ext_vector_type(8))) short short8;       // 8 x bf16 bits (MFMA A/B frag)
typedef __attribute__((ext_vector_type(4))) float floatx4;      // MFMA C/D frag
typedef __attribute__((ext_vector_type(4))) unsigned int uintx4;
typedef __attribute__((ext_vector_type(4))) unsigned short ushort4x;

#define DEV static __device__ __forceinline__

constexpr int NT = 2, NB = 16, NC = 256, NN = 4096, NHD = 8;
constexpr size_t NE1 = (size_t)NT * NB * NC * NN;   // 33554432 elements per output tensor
constexpr size_t TSTRIDE = (size_t)NB * NC * NN;    // t-stride in elements

// ---------- helpers ----------
DEV unsigned short f2bf(float x) {            // round-to-nearest-even fp32 -> bf16 bits
  unsigned int u = __builtin_bit_cast(unsigned int, x);
  unsigned int lsb = (u >> 16) & 1u;
  u += 0x7FFFu + lsb;
  return (unsigned short)(u >> 16);
}
DEV float bfb2f(unsigned short h) {
  unsigned int u = ((unsigned int)h) << 16;
  return __builtin_bit_cast(float, u);
}
DEV unsigned short spike2bf(float s) {        // s is exactly 0.0f or 1.0f -> truncation exact
  return (unsigned short)(__builtin_bit_cast(unsigned int, s) >> 16);
}
DEV unsigned int pk2(unsigned short a, unsigned short b) {
  return (unsigned int)a | ((unsigned int)b << 16);
}
// async global->LDS, 16B per lane; LDS dest must be wave-uniform base + lane*16
typedef __attribute__((address_space(3))) unsigned int lds_u32;
typedef __attribute__((address_space(1))) const unsigned int glb_u32;
DEV void gld_lds16(const void* g, void* l) {
  __builtin_amdgcn_global_load_lds((glb_u32*)g, (lds_u32*)l, 16, 0, 0);
}

// ---------- kernel 1: weight split + BN constant prep ----------
__global__ __launch_bounds__(256) void prep_kernel(
    const float* __restrict__ wq, const float* __restrict__ wk, const float* __restrict__ wv,
    const float* __restrict__ wp, const float* __restrict__ bp,
    const float* __restrict__ qg, const float* __restrict__ qb, const float* __restrict__ qm, const float* __restrict__ qva,
    const float* __restrict__ kg, const float* __restrict__ kb, const float* __restrict__ km, const float* __restrict__ kva,
    const float* __restrict__ vg, const float* __restrict__ vb, const float* __restrict__ vm, const float* __restrict__ vva,
    const float* __restrict__ pg, const float* __restrict__ pb, const float* __restrict__ pm, const float* __restrict__ pva,
    unsigned short* __restrict__ Wqkv, unsigned short* __restrict__ Wp,
    float* __restrict__ invqkv, float* __restrict__ shqkv,
    float* __restrict__ invp, float* __restrict__ shp)
{
  int idx = blockIdx.x * 256 + threadIdx.x;
  if (idx < 196608) {                       // Wq|Wk|Wv stacked [768][256], 3-way bf16 split
    int o = idx >> 8, c = idx & 255;
    const float* src = (o < 256) ? wq : (o < 512) ? wk : wv;
    float w = src[(size_t)(o & 255) * 256 + c];
    unsigned short h0 = f2bf(w);  float f0 = bfb2f(h0);
    float r1 = w - f0;
    unsigned short h1 = f2bf(r1); float f1 = bfb2f(h1);
    float r2 = r1 - f1;
    unsigned short h2 = f2bf(r2);
    Wqkv[idx] = h0; Wqkv[196608 + idx] = h1; Wqkv[393216 + idx] = h2;
  } else if (idx < 262144) {                // Wp [256][256], 3-way split
    int j = idx - 196608;
    float w = wp[j];
    unsigned short h0 = f2bf(w);  float f0 = bfb2f(h0);
    float r1 = w - f0;
    unsigned short h1 = f2bf(r1); float f1 = bfb2f(h1);
    float r2 = r1 - f1;
    unsigned short h2 = f2bf(r2);
    Wp[j] = h0; Wp[65536 + j] = h1; Wp[131072 + j] = h2;
  } else if (idx < 262912) {                // BN constants for q,k,v stacked [768]
    int i = idx - 262144;
    int p = i >> 8, c = i & 255;
    float g  = (p == 0) ? qg[c] : (p == 1) ? kg[c] : vg[c];
    float be = (p == 0) ? qb[c] : (p == 1) ? kb[c] : vb[c];
    float mn = (p == 0) ? qm[c] : (p == 1) ? km[c] : vm[c];
    float vr = (p == 0) ? qva[c] : (p == 1) ? kva[c] : vva[c];
    float sq = sqrtf(vr + 1e-5f);
    invqkv[i] = g / sq;
    shqkv[i]  = be - (mn * g) / sq;
  } else if (idx < 263168) {                // BN constants for p, bias folded in
    int c = idx - 262912;
    float sq = sqrtf(pva[c] + 1e-5f);
    float iv = pg[c] / sq;
    invp[c] = iv;
    shp[c]  = pb[c] - (pm[c] * pg[c]) / sq + bp[c] * iv;
  }
}

// ---------- kernel 2: LIF on x -> xs (fp32 [t,b,c,n]) + bf16 transposed [t,b,n,c] ----------
__global__ __launch_bounds__(256) void lifx_kernel(const float* __restrict__ x,
                                                   float* __restrict__ xs_out,
                                                   unsigned short* __restrict__ xs_t)
{
  __shared__ float tile[2][64][65];
  const int nt = blockIdx.x, ct = blockIdx.y, b = blockIdx.z;
  const int tid = threadIdx.x;
  const int ci = tid >> 2, cq = tid & 3;
  const int n0 = nt * 64, c0 = ct * 64;
  const size_t rowbase = ((size_t)(b * NC + c0 + ci)) * NN + n0 + cq * 16;
  const float* px0 = x + rowbase;
  const float* px1 = x + rowbase + TSTRIDE;
  float* po0 = xs_out + rowbase;
  float* po1 = xs_out + rowbase + TSTRIDE;
  #pragma unroll
  for (int jj = 0; jj < 4; jj++) {
    floatx4 x0 = *(const floatx4*)(px0 + jj * 4);
    floatx4 x1 = *(const floatx4*)(px1 + jj * 4);
    floatx4 s0v, s1v;
    #pragma unroll
    for (int e = 0; e < 4; e++) {
      float v1 = x0[e] * 0.5f;                       // exact
      float s0 = (v1 >= 1.0f) ? 1.0f : 0.0f;
      float vr = v1 * (1.0f - s0);                   // exact (0 or v1)
      float v2 = vr + (x1[e] - vr) * 0.5f;           // same rounding as reference
      float s1 = (v2 >= 1.0f) ? 1.0f : 0.0f;
      s0v[e] = s0; s1v[e] = s1;
      tile[0][ci][cq * 16 + jj * 4 + e] = s0;
      tile[1][ci][cq * 16 + jj * 4 + e] = s1;
    }
    *(floatx4*)(po0 + jj * 4) = s0v;
    *(floatx4*)(po1 + jj * 4) = s1v;
  }
  __syncthreads();
  const int ni = tid >> 2, cg = tid & 3;
  #pragma unroll
  for (int t = 0; t < 2; t++) {
    unsigned short* dst = xs_t + ((size_t)((t * NB + b) * NN) + n0 + ni) * NC + c0 + cg * 16;
    uintx4 w0, w1;
    #pragma unroll
    for (int p2 = 0; p2 < 4; p2++) {
      w0[p2] = pk2(spike2bf(tile[t][cg * 16 + p2 * 2    ][ni]),
                   spike2bf(tile[t][cg * 16 + p2 * 2 + 1][ni]));
      w1[p2] = pk2(spike2bf(tile[t][cg * 16 + p2 * 2 + 8][ni]),
                   spike2bf(tile[t][cg * 16 + p2 * 2 + 9][ni]));
    }
    *(uintx4*)dst = w0;
    *(uintx4*)(dst + 8) = w1;
  }
}

// ---------- kernel 3: fused QKV GEMM + BN + LIF (unchanged from round 3) ----------
__global__ __launch_bounds__(256, 3) void qkv_gemm(
    const unsigned short* __restrict__ xs_t,  // [T][B][N][C] bf16
    const unsigned short* __restrict__ Wsp,   // [3 splits][768][256] bf16
    const float* __restrict__ invv, const float* __restrict__ shv,  // [768]
    float* __restrict__ dq, float* __restrict__ dk, float* __restrict__ dv)
{
  __shared__ __align__(16) unsigned char smem[33280];
  unsigned short* Al = (unsigned short*)smem;            // [3][128][32]
  unsigned short* Bl = (unsigned short*)(smem + 24576);  // [2][64][32]
  float* yl = (float*)smem;                              // [128][65] overlaid for exchange
  const int nt = blockIdx.x, mt = blockIdx.y, b = blockIdx.z;
  const int tid = threadIdx.x;
  const int lane = tid & 63, quad = lane >> 4, l16 = lane & 15;
  const int wave = tid >> 6;
  const int tw = wave >> 1, wm = (wave & 1) * 64;        // waves 0,1: t=0 ; waves 2,3: t=1
  floatx4 acc[4][4] = {};

  for (int k0 = 0; k0 < 256; k0 += 32) {
    __syncthreads();
    #pragma unroll
    for (int j = 0; j < 6; j++) {            // A: 3 splits x 128 rows x 32k
      int ci = j * 256 + tid;
      int s = ci >> 9, j2 = ci & 511, row = j2 >> 2, kk = j2 & 3;
      const unsigned short* g = Wsp + (size_t)s * 196608 + (size_t)(mt * 128 + row) * 256 + k0 + kk * 8;
      gld_lds16(g, Al + ci * 8);
    }
    #pragma unroll
    for (int j = 0; j < 2; j++) {            // B: 2t x 64 rows x 32k
      int ci = j * 256 + tid;
      int t = ci >> 8, j2 = ci & 255, row = j2 >> 2, kk = j2 & 3;
      const unsigned short* g = xs_t + ((size_t)((t * NB + b) * NN) + nt * 64 + row) * NC + k0 + kk * 8;
      gld_lds16(g, Bl + ci * 8);
    }
    __syncthreads();

    short8 bfr[4];
    #pragma unroll
    for (int ni = 0; ni < 4; ni++)
      bfr[ni] = *(const short8*)(Bl + ((size_t)(tw * 64 + ni * 16 + l16)) * 32 + quad * 8);
    #pragma unroll
    for (int mi = 0; mi < 4; mi++) {
      const int arow = wm + mi * 16 + l16;
      short8 a0 = *(const short8*)(Al + ((size_t)(          arow)) * 32 + quad * 8);
      short8 a1 = *(const short8*)(Al + ((size_t)(128  +   arow)) * 32 + quad * 8);
      short8 a2 = *(const short8*)(Al + ((size_t)(256  +   arow)) * 32 + quad * 8);
      #pragma unroll
      for (int ni = 0; ni < 4; ni++) {
        acc[mi][ni] = __builtin_amdgcn_mfma_f32_16x16x32_bf16(a0, bfr[ni], acc[mi][ni], 0, 0, 0);
        acc[mi][ni] = __builtin_amdgcn_mfma_f32_16x16x32_bf16(a1, bfr[ni], acc[mi][ni], 0, 0, 0);
        acc[mi][ni] = __builtin_amdgcn_mfma_f32_16x16x32_bf16(a2, bfr[ni], acc[mi][ni], 0, 0, 0);
      }
    }
  }
  __syncthreads();                 // staging LDS now dead; reuse as exchange
  if (tw == 0) {                   // t0 waves publish raw accumulators
    #pragma unroll
    for (int mi = 0; mi < 4; mi++)
      #pragma unroll
      for (int r = 0; r < 4; r++)
        #pragma unroll
        for (int ni = 0; ni < 4; ni++)
          yl[(size_t)(wm + mi * 16 + quad * 4 + r) * 65 + ni * 16 + l16] = acc[mi][ni][r];
  }
  __syncthreads();
  if (tw == 1) {                   // t1 waves apply BN + 2-step LIF, write both planes
    #pragma unroll
    for (int mi = 0; mi < 4; mi++) {
      #pragma unroll
      for (int r = 0; r < 4; r++) {
        const int lrow = wm + mi * 16 + quad * 4 + r;
        const int orow = mt * 128 + lrow;
        const float iv = invv[orow], sh = shv[orow];
        const int widx = orow >> 8, c = orow & 255;
        float* dst = (widx == 0) ? dq : (widx == 1) ? dk : dv;
        #pragma unroll
        for (int ni = 0; ni < 4; ni++) {
          const int n = nt * 64 + ni * 16 + l16;
          float y0 = yl[(size_t)lrow * 65 + ni * 16 + l16] * iv + sh;
          float y1 = acc[mi][ni][r] * iv + sh;
          float v1 = y0 * 0.5f;
          float s0 = (v1 >= 1.0f) ? 1.0f : 0.0f;
          float vr = v1 * (1.0f - s0);
          float v2 = vr + (y1 - vr) * 0.5f;
          float s1 = (v2 >= 1.0f) ? 1.0f : 0.0f;
          dst[(size_t)(b * NC + c) * NN + n] = s0;
          dst[(size_t)((NB + b) * NC + c) * NN + n] = s1;
        }
      }
    }
  }
}

// ---------- kernel 4: kv partials = K^T V over an N-chunk of 1024 (unchanged) ----------
__global__ __launch_bounds__(256) void kv_kernel(const float* __restrict__ kspk,
                                                 const float* __restrict__ vspk,
                                                 float* __restrict__ kvp)
{
  __shared__ __align__(16) unsigned short Kl[32][264];
  __shared__ __align__(16) unsigned short Vl[32][264];
  const int h = blockIdx.x, z = blockIdx.y, ch = blockIdx.z;   // z = t*16+b, ch = N chunk
  const int tid = threadIdx.x;
  const int wave = tid >> 6, lane = tid & 63, quad = lane >> 4, l16 = lane & 15;
  const int dh = wave & 1, eh = wave >> 1;
  const size_t base = (size_t)z * NC * NN + (size_t)h * 32 * NN + (size_t)ch * 1024;
  floatx4 acc = {0.f, 0.f, 0.f, 0.f};
  for (int n0 = 0; n0 < 1024; n0 += 256) {
    __syncthreads();
    for (int i = tid; i < 2048; i += 256) {             // 32 rows x 64 float4s
      int row = i >> 6, c4 = (i & 63) * 4;
      const size_t g = base + (size_t)row * NN + n0 + c4;
      floatx4 kk = *(const floatx4*)(kspk + g);
      floatx4 vv = *(const floatx4*)(vspk + g);
      ushort4x ks, vs;
      #pragma unroll
      for (int e = 0; e < 4; e++) { ks[e] = spike2bf(kk[e]); vs[e] = spike2bf(vv[e]); }
      *(ushort4x*)&Kl[row][c4] = ks;
      *(ushort4x*)&Vl[row][c4] = vs;
    }
    __syncthreads();
    #pragma unroll
    for (int i = 0; i < 8; i++) {
      short8 ka = *(const short8*)&Kl[dh * 16 + l16][i * 32 + quad * 8];
      short8 vb = *(const short8*)&Vl[eh * 16 + l16][i * 32 + quad * 8];
      acc = __builtin_amdgcn_mfma_f32_16x16x32_bf16(ka, vb, acc, 0, 0, 0);
    }
  }
  float* o = kvp + ((size_t)((ch * 32 + z) * NHD + h)) * 1024;
  #pragma unroll
  for (int r = 0; r < 4; r++)
    o[(dh * 16 + quad * 4 + r) * 32 + eh * 16 + l16] = acc[r];
}

// ---------- kernel 5: attn = 0.125*(q@kv) via exact-integer MFMA, LIF(0.5) -> s spikes ----------
// kv entries are exact integers <= 4096; hi = rne_bf16(v) and lo = v-hi (|lo|<=8) are both
// bf16-exact, q binary => every product and partial sum is an exact fp32 integer < 2^17.
// Result is order-independent and bit-identical to the reference's fp32 computation.
__global__ __launch_bounds__(256) void attn_kernel(const float* __restrict__ qspk,
                                                   const float* __restrict__ kvp,
                                                   unsigned short* __restrict__ s_t)
{
  __shared__ float kvl[2][32][33];                 // pitch 33: frag build 2-way (free)
  __shared__ __align__(8) float ql[32][258];       // pitch 258: A-frag reads 2-way (free)
  const int nb = blockIdx.x, h = blockIdx.y, b = blockIdx.z;
  const int tid = threadIdx.x;
  const int wave = tid >> 6, lane = tid & 63, quad = lane >> 4, l16 = lane & 15;
  // sum 4 exact-integer partials into kvl
  for (int i = tid; i < 2048; i += 256) {
    int t = i >> 10, j = i & 1023;
    size_t o = ((size_t)((t * NB + b) * NHD + h) << 10) + j;
    float v = kvp[o] + kvp[o + 262144] + kvp[o + 524288] + kvp[o + 786432];
    kvl[t][j >> 5][j & 31] = v;
  }
  __syncthreads();
  // B-frags in VGPRs for the whole block: bf[t][split][ehalf]
  short8 bf[2][2][2];
  #pragma unroll
  for (int t = 0; t < 2; t++) {
    #pragma unroll
    for (int eh = 0; eh < 2; eh++) {
      short8 bh, bl;
      #pragma unroll
      for (int j = 0; j < 8; j++) {
        float v = kvl[t][quad * 8 + j][eh * 16 + l16];
        unsigned short h0 = f2bf(v);               // exact: integer multiple of ulp
        float lo = v - bfb2f(h0);                  // exact small integer
        bh[j] = (short)h0;
        bl[j] = (short)f2bf(lo);                   // exact
      }
      bf[t][0][eh] = bh; bf[t][1][eh] = bl;
    }
  }
  floatx4 acc[2][4][2] = {};                        // [t][ntile][ehalf]
  #pragma unroll
  for (int t = 0; t < 2; t++) {
    __syncthreads();
    // stage q tile [32 d][256 n] fp32 (float2, coalesced)
    const float* qp = qspk + ((size_t)((t * NB + b) * NC + h * 32)) * NN + nb * 256;
    for (int i = tid; i < 4096; i += 256) {        // 32 rows x 128 float2
      int row = i >> 7, c2 = (i & 127) * 2;
      *(float2*)&ql[row][c2] = *(const float2*)(qp + (size_t)row * NN + c2);
    }
    __syncthreads();
    #pragma unroll
    for (int nt = 0; nt < 4; nt++) {
      const int nrow = wave * 64 + nt * 16 + l16;
      short8 af;
      #pragma unroll
      for (int j = 0; j < 8; j++)
        af[j] = (short)spike2bf(ql[quad * 8 + j][nrow]);
      #pragma unroll
      for (int eh = 0; eh < 2; eh++) {
        acc[t][nt][eh] = __builtin_amdgcn_mfma_f32_16x16x32_bf16(af, bf[t][0][eh], acc[t][nt][eh], 0, 0, 0);
        acc[t][nt][eh] = __builtin_amdgcn_mfma_f32_16x16x32_bf16(af, bf[t][1][eh], acc[t][nt][eh], 0, 0, 0);
      }
    }
  }
  // epilogue: exact dyadic LIF(0.5) on both t-steps, store bf16 spikes [t,b,n,c]
  const int n0 = nb * 256 + wave * 64;
  #pragma unroll
  for (int nt = 0; nt < 4; nt++) {
    #pragma unroll
    for (int r = 0; r < 4; r++) {
      const int n = n0 + nt * 16 + quad * 4 + r;
      unsigned short* d0 = s_t + ((size_t)(b * NN) + n) * NC + h * 32 + l16;
      unsigned short* d1 = s_t + ((size_t)((NB + b) * NN) + n) * NC + h * 32 + l16;
      #pragma unroll
      for (int eh = 0; eh < 2; eh++) {
        float a0 = acc[0][nt][eh][r] * 0.125f;     // exact dyadic
        float a1 = acc[1][nt][eh][r] * 0.125f;
        float v1 = a0 * 0.5f;
        float s0 = (v1 >= 0.5f) ? 1.f : 0.f;
        float vr = v1 * (1.f - s0);
        float v2 = vr + (a1 - vr) * 0.5f;
        float s1 = (v2 >= 0.5f) ? 1.f : 0.f;
        d0[eh * 16] = s0 != 0.f ? (unsigned short)0x3F80 : (unsigned short)0;
        d1[eh * 16] = s1 != 0.f ? (unsigned short)0x3F80 : (unsigned short)0;
      }
    }
  }
}

// ---------- kernel 6: out = BN(Wp @ s + bp) (unchanged from round 3) ----------
__global__ __launch_bounds__(256, 3) void p_gemm(
    const unsigned short* __restrict__ s_t,   // [T][B][N][C] bf16
    const unsigned short* __restrict__ Wsp,   // [3][256][256]
    const float* __restrict__ invv, const float* __restrict__ shv,
    float* __restrict__ dout)
{
  __shared__ __align__(16) unsigned char smem[32768];
  unsigned short* Al = (unsigned short*)smem;            // [3][128][32]
  unsigned short* Bl = (unsigned short*)(smem + 24576);  // [128][32]
  const int nt = blockIdx.x, mt = blockIdx.y, z = blockIdx.z;  // z = t*16+b
  const int tid = threadIdx.x;
  const int lane = tid & 63, quad = lane >> 4, l16 = lane & 15;
  const int wave = tid >> 6;
  const int wm = (wave & 1) * 64, wn = (wave >> 1) * 64;
  floatx4 acc[4][4] = {};

  for (int k0 = 0; k0 < 256; k0 += 32) {
    __syncthreads();
    #pragma unroll
    for (int j = 0; j < 6; j++) {
      int ci = j * 256 + tid;
      int s = ci >> 9, j2 = ci & 511, row = j2 >> 2, kk = j2 & 3;
      const unsigned short* g = Wsp + (size_t)s * 65536 + (size_t)(mt * 128 + row) * 256 + k0 + kk * 8;
      gld_lds16(g, Al + ci * 8);
    }
    #pragma unroll
    for (int j = 0; j < 2; j++) {
      int ci = j * 256 + tid;
      int row = ci >> 2, kk = ci & 3;
      const unsigned short* g = s_t + ((size_t)(z * NN) + nt * 128 + row) * NC + k0 + kk * 8;
      gld_lds16(g, Bl + ci * 8);
    }
    __syncthreads();

    short8 bfr[4];
    #pragma unroll
    for (int ni = 0; ni < 4; ni++)
      bfr[ni] = *(const short8*)(Bl + ((size_t)(wn + ni * 16 + l16)) * 32 + quad * 8);
    #pragma unroll
    for (int mi = 0; mi < 4; mi++) {
      const int arow = wm + mi * 16 + l16;
      short8 a0 = *(const short8*)(Al + ((size_t)(        arow)) * 32 + quad * 8);
      short8 a1 = *(const short8*)(Al + ((size_t)(128 +   arow)) * 32 + quad * 8);
      short8 a2 = *(const short8*)(Al + ((size_t)(256 +   arow)) * 32 + quad * 8);
      #pragma unroll
      for (int ni = 0; ni < 4; ni++) {
        acc[mi][ni] = __builtin_amdgcn_mfma_f32_16x16x32_bf16(a0, bfr[ni], acc[mi][ni], 0, 0, 0);
        acc[mi][ni] = __builtin_amdgcn_mfma_f32_16x16x32_bf16(a1, bfr[ni], acc[mi][ni], 0, 0, 0);
        acc[mi][ni] = __builtin_amdgcn_mfma_f32_16x16x32_bf16(a2, bfr[ni], acc[mi][ni], 0, 0, 0);
      }
    }
  }
  #pragma unroll
  for (int mi = 0; mi < 4; mi++) {
    #pragma unroll
    for (int r = 0; r < 4; r++) {
      const int orow = mt * 128 + wm + mi * 16 + quad * 4 + r;
      const float iv = invv[orow], sh = shv[orow];
      #pragma unroll
      for (int ni = 0; ni < 4; ni++) {
        const int n = nt * 128 + wn + ni * 16 + l16;
        dout[((size_t)(z * NC + orow)) * NN + n] = acc[mi][ni][r] * iv + sh;
      }
    }
  }
}

// ---------- launch ----------
extern "C" void kernel_launch(void* const* d_in, const int* in_sizes, int n_in,
                              void* d_out, int out_size, void* d_ws, size_t ws_size,
                              hipStream_t stream) {
  (void)in_sizes; (void)n_in; (void)out_size; (void)ws_size;
  const float* x  = (const float*)d_in[0];
  const float* wq = (const float*)d_in[1];
  const float* wk = (const float*)d_in[2];
  const float* wv = (const float*)d_in[3];
  const float* wp = (const float*)d_in[4];
  const float* bp = (const float*)d_in[5];
  const float* qg = (const float*)d_in[6],  *qb = (const float*)d_in[7];
  const float* qm = (const float*)d_in[8],  *qva = (const float*)d_in[9];
  const float* kg = (const float*)d_in[10], *kb = (const float*)d_in[11];
  const float* km = (const float*)d_in[12], *kva = (const float*)d_in[13];
  const float* vg = (const float*)d_in[14], *vb = (const float*)d_in[15];
  const float* vm = (const float*)d_in[16], *vva = (const float*)d_in[17];
  const float* pg = (const float*)d_in[18], *pb = (const float*)d_in[19];
  const float* pm = (const float*)d_in[20], *pva = (const float*)d_in[21];

  float* out = (float*)d_out;       // outputs in return order
  float* xs  = out + NE1;
  float* dq  = out + 2 * NE1;
  float* dk  = out + 3 * NE1;
  float* dv  = out + 4 * NE1;

  // workspace layout; s_t aliases xs_t (xs_t last read by qkv_gemm,
  // s_t first written by attn_kernel two dispatches later)
  char* ws = (char*)d_ws;
  unsigned short* xs_t = (unsigned short*)ws;                   // 67108864 B
  unsigned short* s_t  = (unsigned short*)ws;                   // aliases xs_t
  unsigned short* Wqkv = (unsigned short*)(ws + 67108864);      // 1179648 B
  unsigned short* Wp   = (unsigned short*)(ws + 68288512);      // 393216 B
  float* kvp           = (float*)(ws + 68681728);               // 4194304 B (4 partials)
  float* invqkv        = (float*)(ws + 72876032);               // 768 floats
  float* shqkv         = invqkv + 768;
  float* invp          = shqkv + 768;
  float* shp           = invp + 256;

  prep_kernel<<<1028, 256, 0, stream>>>(wq, wk, wv, wp, bp,
                                        qg, qb, qm, qva, kg, kb, km, kva,
                                        vg, vb, vm, vva, pg, pb, pm, pva,
                                        Wqkv, Wp, invqkv, shqkv, invp, shp);
  lifx_kernel<<<dim3(64, 4, 16), 256, 0, stream>>>(x, xs, xs_t);
  qkv_gemm<<<dim3(64, 6, 16), 256, 0, stream>>>(xs_t, Wqkv, invqkv, shqkv, dq, dk, dv);
  kv_kernel<<<dim3(8, 32, 4), 256, 0, stream>>>(dk, dv, kvp);
  attn_kernel<<<dim3(16, 8, 16), 256, 0, stream>>>(dq, kvp, s_t);
  p_gemm<<<dim3(32, 2, 32), 256, 0, stream>>>(s_t, Wp, invp, shp, out);
}

// Round 5
// 1035.471 us; speedup vs baseline: 1.1435x; 1.0551x over previous
//
#include <hip/hip_runtime.h>
#include <cstdint>
#include <cstddef>

typedef __attribute__((ext_vector_type(8))) short short8;       // 8 x bf16 bits (MFMA A/B frag)
typedef __attribute__((ext_vector_type(4))) float floatx4;      // MFMA C/D frag
typedef __attribute__((ext_vector_type(4))) unsigned int uintx4;
typedef __attribute__((ext_vector_type(4))) unsigned short ushort4x;

#define DEV static __device__ __forceinline__

constexpr int NT = 2, NB = 16, NC = 256, NN = 4096, NHD = 8;
constexpr size_t NE1 = (size_t)NT * NB * NC * NN;   // elements per output tensor
constexpr size_t TSTRIDE = (size_t)NB * NC * NN;    // t-stride in elements

// ---------- helpers ----------
DEV unsigned short f2bf(float x) {            // round-to-nearest-even fp32 -> bf16 bits
  unsigned int u = __builtin_bit_cast(unsigned int, x);
  unsigned int lsb = (u >> 16) & 1u;
  u += 0x7FFFu + lsb;
  return (unsigned short)(u >> 16);
}
DEV float bfb2f(unsigned short h) {
  unsigned int u = ((unsigned int)h) << 16;
  return __builtin_bit_cast(float, u);
}
DEV unsigned short spike2bf(float s) {        // s is exactly 0.0f or 1.0f -> truncation exact
  return (unsigned short)(__builtin_bit_cast(unsigned int, s) >> 16);
}
DEV unsigned int pk2(unsigned short a, unsigned short b) {
  return (unsigned int)a | ((unsigned int)b << 16);
}
// bank-conflict-free slot mapping for [rows][32 bf16] tiles staged via global_load_lds:
// chunk kk (16B) of row fr lives at slot fr*4 + (kk ^ ((fr>>1)&3)).  Removes the
// 4/8-way ds_read_b128 phase conflicts of the naive 64B-pitch layout (2 rows/bank-group).
DEV int swz(int fr, int kk) { return fr * 4 + (kk ^ ((fr >> 1) & 3)); }
// async global->LDS, 16B per lane; LDS dest is wave-uniform base + lane*16 (global ptr per-lane free)
typedef __attribute__((address_space(3))) unsigned int lds_u32;
typedef __attribute__((address_space(1))) const unsigned int glb_u32;
DEV void gld_lds16(const void* g, void* l) {
  __builtin_amdgcn_global_load_lds((glb_u32*)g, (lds_u32*)l, 16, 0, 0);
}

// ---------- kernel 1: weight split + BN constant prep ----------
__global__ __launch_bounds__(256) void prep_kernel(
    const float* __restrict__ wq, const float* __restrict__ wk, const float* __restrict__ wv,
    const float* __restrict__ wp, const float* __restrict__ bp,
    const float* __restrict__ qg, const float* __restrict__ qb, const float* __restrict__ qm, const float* __restrict__ qva,
    const float* __restrict__ kg, const float* __restrict__ kb, const float* __restrict__ km, const float* __restrict__ kva,
    const float* __restrict__ vg, const float* __restrict__ vb, const float* __restrict__ vm, const float* __restrict__ vva,
    const float* __restrict__ pg, const float* __restrict__ pb, const float* __restrict__ pm, const float* __restrict__ pva,
    unsigned short* __restrict__ Wqkv, unsigned short* __restrict__ Wp,
    float* __restrict__ invqkv, float* __restrict__ shqkv,
    float* __restrict__ invp, float* __restrict__ shp)
{
  int idx = blockIdx.x * 256 + threadIdx.x;
  if (idx < 196608) {                       // Wq|Wk|Wv stacked [768][256], 3-way bf16 split
    int o = idx >> 8, c = idx & 255;
    const float* src = (o < 256) ? wq : (o < 512) ? wk : wv;
    float w = src[(size_t)(o & 255) * 256 + c];
    unsigned short h0 = f2bf(w);  float f0 = bfb2f(h0);
    float r1 = w - f0;
    unsigned short h1 = f2bf(r1); float f1 = bfb2f(h1);
    float r2 = r1 - f1;
    unsigned short h2 = f2bf(r2);
    Wqkv[idx] = h0; Wqkv[196608 + idx] = h1; Wqkv[393216 + idx] = h2;
  } else if (idx < 262144) {                // Wp [256][256], 3-way split
    int j = idx - 196608;
    float w = wp[j];
    unsigned short h0 = f2bf(w);  float f0 = bfb2f(h0);
    float r1 = w - f0;
    unsigned short h1 = f2bf(r1); float f1 = bfb2f(h1);
    float r2 = r1 - f1;
    unsigned short h2 = f2bf(r2);
    Wp[j] = h0; Wp[65536 + j] = h1; Wp[131072 + j] = h2;
  } else if (idx < 262912) {                // BN constants for q,k,v stacked [768]
    int i = idx - 262144;
    int p = i >> 8, c = i & 255;
    float g  = (p == 0) ? qg[c] : (p == 1) ? kg[c] : vg[c];
    float be = (p == 0) ? qb[c] : (p == 1) ? kb[c] : vb[c];
    float mn = (p == 0) ? qm[c] : (p == 1) ? km[c] : vm[c];
    float vr = (p == 0) ? qva[c] : (p == 1) ? kva[c] : vva[c];
    float sq = sqrtf(vr + 1e-5f);
    invqkv[i] = g / sq;
    shqkv[i]  = be - (mn * g) / sq;
  } else if (idx < 263168) {                // BN constants for p, bias folded in
    int c = idx - 262912;
    float sq = sqrtf(pva[c] + 1e-5f);
    float iv = pg[c] / sq;
    invp[c] = iv;
    shp[c]  = pb[c] - (pm[c] * pg[c]) / sq + bp[c] * iv;
  }
}

// ---------- kernel 2: LIF on x -> xs (fp32 [t,b,c,n]) + bf16 transposed [t,b,n,c] ----------
__global__ __launch_bounds__(256) void lifx_kernel(const float* __restrict__ x,
                                                   float* __restrict__ xs_out,
                                                   unsigned short* __restrict__ xs_t)
{
  __shared__ float tile[2][64][65];
  const int nt = blockIdx.x, ct = blockIdx.y, b = blockIdx.z;
  const int tid = threadIdx.x;
  const int ci = tid >> 2, cq = tid & 3;
  const int n0 = nt * 64, c0 = ct * 64;
  const size_t rowbase = ((size_t)(b * NC + c0 + ci)) * NN + n0 + cq * 16;
  const float* px0 = x + rowbase;
  const float* px1 = x + rowbase + TSTRIDE;
  float* po0 = xs_out + rowbase;
  float* po1 = xs_out + rowbase + TSTRIDE;
  #pragma unroll
  for (int jj = 0; jj < 4; jj++) {
    floatx4 x0 = *(const floatx4*)(px0 + jj * 4);
    floatx4 x1 = *(const floatx4*)(px1 + jj * 4);
    floatx4 s0v, s1v;
    #pragma unroll
    for (int e = 0; e < 4; e++) {
      float v1 = x0[e] * 0.5f;                       // exact
      float s0 = (v1 >= 1.0f) ? 1.0f : 0.0f;
      float vr = v1 * (1.0f - s0);                   // exact (0 or v1)
      float v2 = vr + (x1[e] - vr) * 0.5f;           // same rounding as reference
      float s1 = (v2 >= 1.0f) ? 1.0f : 0.0f;
      s0v[e] = s0; s1v[e] = s1;
      tile[0][ci][cq * 16 + jj * 4 + e] = s0;
      tile[1][ci][cq * 16 + jj * 4 + e] = s1;
    }
    *(floatx4*)(po0 + jj * 4) = s0v;
    *(floatx4*)(po1 + jj * 4) = s1v;
  }
  __syncthreads();
  const int ni = tid >> 2, cg = tid & 3;
  #pragma unroll
  for (int t = 0; t < 2; t++) {
    unsigned short* dst = xs_t + ((size_t)((t * NB + b) * NN) + n0 + ni) * NC + c0 + cg * 16;
    uintx4 w0, w1;
    #pragma unroll
    for (int p2 = 0; p2 < 4; p2++) {
      w0[p2] = pk2(spike2bf(tile[t][cg * 16 + p2 * 2    ][ni]),
                   spike2bf(tile[t][cg * 16 + p2 * 2 + 1][ni]));
      w1[p2] = pk2(spike2bf(tile[t][cg * 16 + p2 * 2 + 8][ni]),
                   spike2bf(tile[t][cg * 16 + p2 * 2 + 9][ni]));
    }
    *(uintx4*)dst = w0;
    *(uintx4*)(dst + 8) = w1;
  }
}

// ---------- kernel 3: fused QKV GEMM + BN + LIF -> fp32 spikes + bit-planes ----------
// Swizzled LDS slots (conflict-free frag reads).  Epilogue also emits per-row bit masks
// via __ballot: bits16[z][c][n>>4], bit = n&15  (exact bool of the fp32 spikes).
__global__ __launch_bounds__(256, 3) void qkv_gemm(
    const unsigned short* __restrict__ xs_t,  // [T][B][N][C] bf16
    const unsigned short* __restrict__ Wsp,   // [3 splits][768][256] bf16
    const float* __restrict__ invv, const float* __restrict__ shv,  // [768]
    float* __restrict__ dq, float* __restrict__ dk, float* __restrict__ dv,
    unsigned short* __restrict__ qbits, unsigned short* __restrict__ kbits,
    unsigned short* __restrict__ vbits)
{
  __shared__ __align__(16) unsigned char smem[33280];
  unsigned short* Al = (unsigned short*)smem;            // 1536 slots (3 splits x 128 rows x 4)
  unsigned short* Bl = (unsigned short*)(smem + 24576);  // 512 slots (2t x 64 rows x 4)
  float* yl = (float*)smem;                              // [128][65] overlaid for exchange
  const int nt = blockIdx.x, mt = blockIdx.y, b = blockIdx.z;
  const int tid = threadIdx.x;
  const int lane = tid & 63, quad = lane >> 4, l16 = lane & 15;
  const int wave = tid >> 6;
  const int tw = wave >> 1, wm = (wave & 1) * 64;        // waves 0,1: t=0 ; waves 2,3: t=1
  floatx4 acc[4][4] = {};

  for (int k0 = 0; k0 < 256; k0 += 32) {
    __syncthreads();
    #pragma unroll
    for (int j = 0; j < 6; j++) {            // A: slots [0,1536)
      int ci = j * 256 + tid;
      int fr = ci >> 2;
      int kk = (ci & 3) ^ ((fr >> 1) & 3);
      int s = fr >> 7, row = fr & 127;
      const unsigned short* g = Wsp + (size_t)s * 196608 + (size_t)(mt * 128 + row) * 256 + k0 + kk * 8;
      gld_lds16(g, Al + (size_t)ci * 8);
    }
    #pragma unroll
    for (int j = 0; j < 2; j++) {            // B: slots [0,512)
      int ci = j * 256 + tid;
      int fr = ci >> 2;
      int kk = (ci & 3) ^ ((fr >> 1) & 3);
      int t = fr >> 6, row = fr & 63;
      const unsigned short* g = xs_t + ((size_t)((t * NB + b) * NN) + nt * 64 + row) * NC + k0 + kk * 8;
      gld_lds16(g, Bl + (size_t)ci * 8);
    }
    __syncthreads();

    short8 bfr[4];
    #pragma unroll
    for (int ni = 0; ni < 4; ni++) {
      int fr = tw * 64 + ni * 16 + l16;
      bfr[ni] = *(const short8*)(Bl + (size_t)swz(fr, quad) * 8);
    }
    #pragma unroll
    for (int mi = 0; mi < 4; mi++) {
      const int r0 = wm + mi * 16 + l16;
      short8 a0 = *(const short8*)(Al + (size_t)swz(      r0, quad) * 8);
      short8 a1 = *(const short8*)(Al + (size_t)swz(128 + r0, quad) * 8);
      short8 a2 = *(const short8*)(Al + (size_t)swz(256 + r0, quad) * 8);
      #pragma unroll
      for (int ni = 0; ni < 4; ni++) {
        acc[mi][ni] = __builtin_amdgcn_mfma_f32_16x16x32_bf16(a0, bfr[ni], acc[mi][ni], 0, 0, 0);
        acc[mi][ni] = __builtin_amdgcn_mfma_f32_16x16x32_bf16(a1, bfr[ni], acc[mi][ni], 0, 0, 0);
        acc[mi][ni] = __builtin_amdgcn_mfma_f32_16x16x32_bf16(a2, bfr[ni], acc[mi][ni], 0, 0, 0);
      }
    }
  }
  __syncthreads();                 // staging LDS now dead; reuse as exchange
  if (tw == 0) {                   // t0 waves publish raw accumulators
    #pragma unroll
    for (int mi = 0; mi < 4; mi++)
      #pragma unroll
      for (int r = 0; r < 4; r++)
        #pragma unroll
        for (int ni = 0; ni < 4; ni++)
          yl[(size_t)(wm + mi * 16 + quad * 4 + r) * 65 + ni * 16 + l16] = acc[mi][ni][r];
  }
  __syncthreads();
  if (tw == 1) {                   // t1 waves apply BN + 2-step LIF, write both planes + bits
    #pragma unroll
    for (int mi = 0; mi < 4; mi++) {
      #pragma unroll
      for (int r = 0; r < 4; r++) {
        const int lrow = wm + mi * 16 + quad * 4 + r;
        const int orow = mt * 128 + lrow;
        const float iv = invv[orow], sh = shv[orow];
        const int widx = orow >> 8, c = orow & 255;
        float* dst = (widx == 0) ? dq : (widx == 1) ? dk : dv;
        unsigned short* bb = (widx == 0) ? qbits : (widx == 1) ? kbits : vbits;
        #pragma unroll
        for (int ni = 0; ni < 4; ni++) {
          const int n = nt * 64 + ni * 16 + l16;
          float y0 = yl[(size_t)lrow * 65 + ni * 16 + l16] * iv + sh;
          float y1 = acc[mi][ni][r] * iv + sh;
          float v1 = y0 * 0.5f;
          float s0 = (v1 >= 1.0f) ? 1.0f : 0.0f;
          float vr = v1 * (1.0f - s0);
          float v2 = vr + (y1 - vr) * 0.5f;
          float s1 = (v2 >= 1.0f) ? 1.0f : 0.0f;
          dst[(size_t)(b * NC + c) * NN + n] = s0;
          dst[(size_t)((NB + b) * NC + c) * NN + n] = s1;
          unsigned long long bl0 = __ballot(s0 != 0.0f);   // bit(lane)=quad*16+l16
          unsigned long long bl1 = __ballot(s1 != 0.0f);
          if (l16 == 0) {          // field quad = 16 n-bits of this lane's row c
            const int w16 = nt * 4 + ni;
            bb[(size_t)b        * 65536 + (size_t)c * 256 + w16] = (unsigned short)(bl0 >> (quad * 16));
            bb[(size_t)(NB + b) * 65536 + (size_t)c * 256 + w16] = (unsigned short)(bl1 >> (quad * 16));
          }
        }
      }
    }
  }
}

// ---------- kernel 4: kv = K^T V via popcount over bit-planes (exact integers) ----------
__global__ __launch_bounds__(256) void kv_kernel(const unsigned long long* __restrict__ kb,
                                                 const unsigned long long* __restrict__ vb,
                                                 float* __restrict__ kvout)
{
  __shared__ unsigned long long Kl[32 * 65];   // pitch 65 u64
  __shared__ unsigned long long Vl[32 * 65];
  const int h = blockIdx.x, z = blockIdx.y;    // z = t*16+b
  const int tid = threadIdx.x;
  for (int i = tid; i < 2048; i += 256) {
    int row = i >> 6, w = i & 63;
    size_t g = (size_t)z * 16384 + (size_t)(h * 32 + row) * 64 + w;
    Kl[row * 65 + w] = kb[g];
    Vl[row * 65 + w] = vb[g];
  }
  __syncthreads();
  const int d = tid & 31, e0 = tid >> 5;       // thread: row d x 4 cols (e0+8p)
  int acc0 = 0, acc1 = 0, acc2 = 0, acc3 = 0;
  for (int w = 0; w < 64; w++) {
    unsigned long long ku = Kl[d * 65 + w];
    acc0 += __popcll(ku & Vl[(e0     ) * 65 + w]);
    acc1 += __popcll(ku & Vl[(e0 +  8) * 65 + w]);
    acc2 += __popcll(ku & Vl[(e0 + 16) * 65 + w]);
    acc3 += __popcll(ku & Vl[(e0 + 24) * 65 + w]);
  }
  float* o = kvout + ((size_t)(z * NHD + h) << 10);
  o[d * 32 + e0     ] = (float)acc0;
  o[d * 32 + e0 +  8] = (float)acc1;
  o[d * 32 + e0 + 16] = (float)acc2;
  o[d * 32 + e0 + 24] = (float)acc3;
}

// ---------- kernel 5: attn = 0.125*(q@kv) via exact-integer MFMA, LIF(0.5) -> s bit-plane ----------
// q frags built from qbits (identical 0/1 values).  kv split hi/lo bf16 (exact ints).
// Epilogue emits sbits16[z][n][c>>4] (bit = c&15) via __ballot — p_gemm's B layout.
__global__ __launch_bounds__(256) void attn_kernel(const unsigned short* __restrict__ qb16,
                                                   const float* __restrict__ kvout,
                                                   unsigned short* __restrict__ sb16)
{
  __shared__ float kvl[2][32][33];
  __shared__ unsigned short qt[2][32][16];    // q bit-words: [t][d][n-word]
  const int nb = blockIdx.x, h = blockIdx.y, b = blockIdx.z;
  const int tid = threadIdx.x;
  const int wave = tid >> 6, lane = tid & 63, quad = lane >> 4, l16 = lane & 15;
  for (int i = tid; i < 2048; i += 256) {
    int t = i >> 10, j = i & 1023;
    kvl[t][j >> 5][j & 31] = kvout[((size_t)((t * NB + b) * NHD + h) << 10) + j];
  }
  for (int i = tid; i < 1024; i += 256) {
    int t = i >> 9, j = i & 511, row = j >> 4, w = j & 15;
    qt[t][row][w] = qb16[(size_t)(t * NB + b) * 65536 + (size_t)(h * 32 + row) * 256 + nb * 16 + w];
  }
  __syncthreads();
  // B-frags: kv split into exact bf16 hi+lo (integers <=4096; |lo|<=8; both exact)
  short8 bf[2][2][2];
  #pragma unroll
  for (int t = 0; t < 2; t++) {
    #pragma unroll
    for (int eh = 0; eh < 2; eh++) {
      short8 bh, bl;
      #pragma unroll
      for (int j = 0; j < 8; j++) {
        float v = kvl[t][quad * 8 + j][eh * 16 + l16];
        unsigned short h0 = f2bf(v);
        float lo = v - bfb2f(h0);
        bh[j] = (short)h0;
        bl[j] = (short)f2bf(lo);
      }
      bf[t][0][eh] = bh; bf[t][1][eh] = bl;
    }
  }
  floatx4 acc[2][4][2] = {};                   // [t][ntile][ehalf]
  #pragma unroll
  for (int t = 0; t < 2; t++) {
    #pragma unroll
    for (int nt = 0; nt < 4; nt++) {
      const int wv = wave * 4 + nt;            // n-word index of this tile
      short8 af;
      #pragma unroll
      for (int j = 0; j < 8; j++) {            // broadcast u16 read + per-lane bit test
        unsigned short w = qt[t][quad * 8 + j][wv];
        af[j] = (short)(((w >> l16) & 1) ? 0x3F80 : 0);
      }
      #pragma unroll
      for (int eh = 0; eh < 2; eh++) {
        acc[t][nt][eh] = __builtin_amdgcn_mfma_f32_16x16x32_bf16(af, bf[t][0][eh], acc[t][nt][eh], 0, 0, 0);
        acc[t][nt][eh] = __builtin_amdgcn_mfma_f32_16x16x32_bf16(af, bf[t][1][eh], acc[t][nt][eh], 0, 0, 0);
      }
    }
  }
  // epilogue: exact dyadic LIF(0.5); pack spikes as bits (16 c per n-row)
  const int n0 = nb * 256 + wave * 64;
  #pragma unroll
  for (int nt = 0; nt < 4; nt++) {
    #pragma unroll
    for (int r = 0; r < 4; r++) {
      const int n = n0 + nt * 16 + quad * 4 + r;          // per-lane (quad)
      #pragma unroll
      for (int eh = 0; eh < 2; eh++) {
        float a0 = acc[0][nt][eh][r] * 0.125f;            // exact dyadic
        float a1 = acc[1][nt][eh][r] * 0.125f;
        float v1 = a0 * 0.5f;
        float s0 = (v1 >= 0.5f) ? 1.f : 0.f;
        float vr = v1 * (1.f - s0);
        float v2 = vr + (a1 - vr) * 0.5f;
        float s1 = (v2 >= 0.5f) ? 1.f : 0.f;
        unsigned long long bl0 = __ballot(s0 != 0.f);     // field quad = 16 c-bits of n(quad)
        unsigned long long bl1 = __ballot(s1 != 0.f);
        if (l16 == 0) {
          const int w16 = h * 2 + eh;
          sb16[(size_t)b        * 65536 + (size_t)n * 16 + w16] = (unsigned short)(bl0 >> (quad * 16));
          sb16[(size_t)(NB + b) * 65536 + (size_t)n * 16 + w16] = (unsigned short)(bl1 >> (quad * 16));
        }
      }
    }
  }
}

// ---------- kernel 6: out = BN(Wp @ s + bp); B unpacked from sbits; swizzled LDS ----------
__global__ __launch_bounds__(256, 3) void p_gemm(
    const unsigned short* __restrict__ sb16,  // [z][n][c-word] bit-plane
    const unsigned short* __restrict__ Wsp,   // [3][256][256]
    const float* __restrict__ invv, const float* __restrict__ shv,
    float* __restrict__ dout)
{
  __shared__ __align__(16) unsigned char smem[32768];
  unsigned short* Al = (unsigned short*)smem;            // 1536 slots
  unsigned short* Bl = (unsigned short*)(smem + 24576);  // 512 slots (128 rows x 4)
  const int nt = blockIdx.x, mt = blockIdx.y, z = blockIdx.z;  // z = t*16+b
  const int tid = threadIdx.x;
  const int lane = tid & 63, quad = lane >> 4, l16 = lane & 15;
  const int wave = tid >> 6;
  const int wm = (wave & 1) * 64, wn = (wave >> 1) * 64;
  floatx4 acc[4][4] = {};
  const int brow = tid & 127, bhalf = tid >> 7;

  for (int k0 = 0; k0 < 256; k0 += 32) {
    __syncthreads();
    #pragma unroll
    for (int j = 0; j < 6; j++) {            // A via async copy, swizzled slots
      int ci = j * 256 + tid;
      int fr = ci >> 2;
      int kk = (ci & 3) ^ ((fr >> 1) & 3);
      int s = fr >> 7, row = fr & 127;
      const unsigned short* g = Wsp + (size_t)s * 65536 + (size_t)(mt * 128 + row) * 256 + k0 + kk * 8;
      gld_lds16(g, Al + (size_t)ci * 8);
    }
    {                                        // B: unpack 16 bits -> 16 bf16 per thread
      unsigned short wb = sb16[(size_t)z * 65536 + (size_t)(nt * 128 + brow) * 16 + (k0 >> 4) + bhalf];
      uintx4 lo4, hi4;
      #pragma unroll
      for (int p = 0; p < 4; p++) {
        lo4[p] = pk2(((wb >> (2 * p)) & 1) ? 0x3F80 : 0, ((wb >> (2 * p + 1)) & 1) ? 0x3F80 : 0);
        hi4[p] = pk2(((wb >> (8 + 2 * p)) & 1) ? 0x3F80 : 0, ((wb >> (9 + 2 * p)) & 1) ? 0x3F80 : 0);
      }
      *(uintx4*)(Bl + (size_t)swz(brow, bhalf * 2)     * 8) = lo4;
      *(uintx4*)(Bl + (size_t)swz(brow, bhalf * 2 + 1) * 8) = hi4;
    }
    __syncthreads();

    short8 bfr[4];
    #pragma unroll
    for (int ni = 0; ni < 4; ni++) {
      int fr = wn + ni * 16 + l16;
      bfr[ni] = *(const short8*)(Bl + (size_t)swz(fr, quad) * 8);
    }
    #pragma unroll
    for (int mi = 0; mi < 4; mi++) {
      const int r0 = wm + mi * 16 + l16;
      short8 a0 = *(const short8*)(Al + (size_t)swz(      r0, quad) * 8);
      short8 a1 = *(const short8*)(Al + (size_t)swz(128 + r0, quad) * 8);
      short8 a2 = *(const short8*)(Al + (size_t)swz(256 + r0, quad) * 8);
      #pragma unroll
      for (int ni = 0; ni < 4; ni++) {
        acc[mi][ni] = __builtin_amdgcn_mfma_f32_16x16x32_bf16(a0, bfr[ni], acc[mi][ni], 0, 0, 0);
        acc[mi][ni] = __builtin_amdgcn_mfma_f32_16x16x32_bf16(a1, bfr[ni], acc[mi][ni], 0, 0, 0);
        acc[mi][ni] = __builtin_amdgcn_mfma_f32_16x16x32_bf16(a2, bfr[ni], acc[mi][ni], 0, 0, 0);
      }
    }
  }
  #pragma unroll
  for (int mi = 0; mi < 4; mi++) {
    #pragma unroll
    for (int r = 0; r < 4; r++) {
      const int orow = mt * 128 + wm + mi * 16 + quad * 4 + r;
      const float iv = invv[orow], sh = shv[orow];
      #pragma unroll
      for (int ni = 0; ni < 4; ni++) {
        const int n = nt * 128 + wn + ni * 16 + l16;
        dout[((size_t)(z * NC + orow)) * NN + n] = acc[mi][ni][r] * iv + sh;
      }
    }
  }
}

// ---------- launch ----------
extern "C" void kernel_launch(void* const* d_in, const int* in_sizes, int n_in,
                              void* d_out, int out_size, void* d_ws, size_t ws_size,
                              hipStream_t stream) {
  (void)in_sizes; (void)n_in; (void)out_size; (void)ws_size;
  const float* x  = (const float*)d_in[0];
  const float* wq = (const float*)d_in[1];
  const float* wk = (const float*)d_in[2];
  const float* wv = (const float*)d_in[3];
  const float* wp = (const float*)d_in[4];
  const float* bp = (const float*)d_in[5];
  const float* qg = (const float*)d_in[6],  *qb = (const float*)d_in[7];
  const float* qm = (const float*)d_in[8],  *qva = (const float*)d_in[9];
  const float* kg = (const float*)d_in[10], *kb = (const float*)d_in[11];
  const float* km = (const float*)d_in[12], *kva = (const float*)d_in[13];
  const float* vg = (const float*)d_in[14], *vb = (const float*)d_in[15];
  const float* vm = (const float*)d_in[16], *vva = (const float*)d_in[17];
  const float* pg = (const float*)d_in[18], *pb = (const float*)d_in[19];
  const float* pm = (const float*)d_in[20], *pva = (const float*)d_in[21];

  float* out = (float*)d_out;       // outputs in return order
  float* xs  = out + NE1;
  float* dq  = out + 2 * NE1;
  float* dk  = out + 3 * NE1;
  float* dv  = out + 4 * NE1;

  char* ws = (char*)d_ws;
  unsigned short* xs_t  = (unsigned short*)ws;                  // 67108864 B
  unsigned short* Wqkv  = (unsigned short*)(ws + 67108864);     // 1179648 B
  unsigned short* Wp    = (unsigned short*)(ws + 68288512);     // 393216 B
  float* kvout          = (float*)(ws + 68681728);              // 1048576 B
  unsigned short* qbits = (unsigned short*)(ws + 69730304);     // 4194304 B
  unsigned short* kbits = (unsigned short*)(ws + 73924608);     // 4194304 B
  unsigned short* vbits = (unsigned short*)(ws + 78118912);     // 4194304 B
  unsigned short* sbits = (unsigned short*)(ws + 82313216);     // 4194304 B
  float* invqkv         = (float*)(ws + 86507520);              // 768 floats
  float* shqkv          = invqkv + 768;
  float* invp           = shqkv + 768;
  float* shp            = invp + 256;

  prep_kernel<<<1028, 256, 0, stream>>>(wq, wk, wv, wp, bp,
                                        qg, qb, qm, qva, kg, kb, km, kva,
                                        vg, vb, vm, vva, pg, pb, pm, pva,
                                        Wqkv, Wp, invqkv, shqkv, invp, shp);
  lifx_kernel<<<dim3(64, 4, 16), 256, 0, stream>>>(x, xs, xs_t);
  qkv_gemm<<<dim3(64, 6, 16), 256, 0, stream>>>(xs_t, Wqkv, invqkv, shqkv,
                                                dq, dk, dv, qbits, kbits, vbits);
  kv_kernel<<<dim3(8, 32), 256, 0, stream>>>((const unsigned long long*)kbits,
                                             (const unsigned long long*)vbits, kvout);
  attn_kernel<<<dim3(16, 8, 16), 256, 0, stream>>>(qbits, kvout, sbits);
  p_gemm<<<dim3(32, 2, 32), 256, 0, stream>>>(sbits, Wp, invp, shp, out);
}

// Round 6
// 974.526 us; speedup vs baseline: 1.2150x; 1.0625x over previous
//
#include <hip/hip_runtime.h>
#include <cstdint>
#include <cstddef>

typedef __attribute__((ext_vector_type(8))) short short8;       // 8 x bf16 bits (MFMA A/B frag)
typedef __attribute__((ext_vector_type(4))) float floatx4;      // MFMA C/D frag
typedef __attribute__((ext_vector_type(4))) unsigned int uintx4;

#define DEV static __device__ __forceinline__

constexpr int NT = 2, NB = 16, NC = 256, NN = 4096, NHD = 8;
constexpr size_t NE1 = (size_t)NT * NB * NC * NN;   // elements per output tensor
constexpr size_t TSTRIDE = (size_t)NB * NC * NN;    // t-stride in elements

// ---------- helpers ----------
DEV unsigned short f2bf(float x) {            // round-to-nearest-even fp32 -> bf16 bits
  unsigned int u = __builtin_bit_cast(unsigned int, x);
  unsigned int lsb = (u >> 16) & 1u;
  u += 0x7FFFu + lsb;
  return (unsigned short)(u >> 16);
}
DEV float bfb2f(unsigned short h) {
  unsigned int u = ((unsigned int)h) << 16;
  return __builtin_bit_cast(float, u);
}
DEV unsigned int pk2(unsigned short a, unsigned short b) {
  return (unsigned int)a | ((unsigned int)b << 16);
}
// bank-conflict-free slot mapping for [rows][32 bf16] tiles: chunk kk (16B) of row fr
// lives at slot fr*4 + (kk ^ ((fr>>1)&3)).
DEV int swz(int fr, int kk) { return fr * 4 + (kk ^ ((fr >> 1) & 3)); }
// async global->LDS, 16B per lane; LDS dest is wave-uniform base + lane*16
typedef __attribute__((address_space(3))) unsigned int lds_u32;
typedef __attribute__((address_space(1))) const unsigned int glb_u32;
DEV void gld_lds16(const void* g, void* l) {
  __builtin_amdgcn_global_load_lds((glb_u32*)g, (lds_u32*)l, 16, 0, 0);
}

// ---------- kernel 1: weight split + BN constant prep ----------
__global__ __launch_bounds__(256) void prep_kernel(
    const float* __restrict__ wq, const float* __restrict__ wk, const float* __restrict__ wv,
    const float* __restrict__ wp, const float* __restrict__ bp,
    const float* __restrict__ qg, const float* __restrict__ qb, const float* __restrict__ qm, const float* __restrict__ qva,
    const float* __restrict__ kg, const float* __restrict__ kb, const float* __restrict__ km, const float* __restrict__ kva,
    const float* __restrict__ vg, const float* __restrict__ vb, const float* __restrict__ vm, const float* __restrict__ vva,
    const float* __restrict__ pg, const float* __restrict__ pb, const float* __restrict__ pm, const float* __restrict__ pva,
    unsigned short* __restrict__ Wqkv, unsigned short* __restrict__ Wp,
    float* __restrict__ invqkv, float* __restrict__ shqkv,
    float* __restrict__ invp, float* __restrict__ shp)
{
  int idx = blockIdx.x * 256 + threadIdx.x;
  if (idx < 196608) {                       // Wq|Wk|Wv stacked [768][256], 3-way bf16 split
    int o = idx >> 8, c = idx & 255;
    const float* src = (o < 256) ? wq : (o < 512) ? wk : wv;
    float w = src[(size_t)(o & 255) * 256 + c];
    unsigned short h0 = f2bf(w);  float f0 = bfb2f(h0);
    float r1 = w - f0;
    unsigned short h1 = f2bf(r1); float f1 = bfb2f(h1);
    float r2 = r1 - f1;
    unsigned short h2 = f2bf(r2);
    Wqkv[idx] = h0; Wqkv[196608 + idx] = h1; Wqkv[393216 + idx] = h2;
  } else if (idx < 262144) {                // Wp [256][256], 3-way split
    int j = idx - 196608;
    float w = wp[j];
    unsigned short h0 = f2bf(w);  float f0 = bfb2f(h0);
    float r1 = w - f0;
    unsigned short h1 = f2bf(r1); float f1 = bfb2f(h1);
    float r2 = r1 - f1;
    unsigned short h2 = f2bf(r2);
    Wp[j] = h0; Wp[65536 + j] = h1; Wp[131072 + j] = h2;
  } else if (idx < 262912) {                // BN constants for q,k,v stacked [768]
    int i = idx - 262144;
    int p = i >> 8, c = i & 255;
    float g  = (p == 0) ? qg[c] : (p == 1) ? kg[c] : vg[c];
    float be = (p == 0) ? qb[c] : (p == 1) ? kb[c] : vb[c];
    float mn = (p == 0) ? qm[c] : (p == 1) ? km[c] : vm[c];
    float vr = (p == 0) ? qva[c] : (p == 1) ? kva[c] : vva[c];
    float sq = sqrtf(vr + 1e-5f);
    invqkv[i] = g / sq;
    shqkv[i]  = be - (mn * g) / sq;
  } else if (idx < 263168) {                // BN constants for p, bias folded in
    int c = idx - 262912;
    float sq = sqrtf(pva[c] + 1e-5f);
    float iv = pg[c] / sq;
    invp[c] = iv;
    shp[c]  = pb[c] - (pm[c] * pg[c]) / sq + bp[c] * iv;
  }
}

// ---------- kernel 2: LIF on x -> xs (fp32 [t,b,c,n]) + bit-plane xbits [z][n][c-word] ----------
__global__ __launch_bounds__(256) void lifx_kernel(const float* __restrict__ x,
                                                   float* __restrict__ xs_out,
                                                   unsigned short* __restrict__ xb16)
{
  __shared__ float tile[2][64][65];
  const int nt = blockIdx.x, ct = blockIdx.y, b = blockIdx.z;
  const int tid = threadIdx.x;
  const int ci = tid >> 2, cq = tid & 3;
  const int n0 = nt * 64, c0 = ct * 64;
  const size_t rowbase = ((size_t)(b * NC + c0 + ci)) * NN + n0 + cq * 16;
  const float* px0 = x + rowbase;
  const float* px1 = x + rowbase + TSTRIDE;
  float* po0 = xs_out + rowbase;
  float* po1 = xs_out + rowbase + TSTRIDE;
  #pragma unroll
  for (int jj = 0; jj < 4; jj++) {
    floatx4 x0 = *(const floatx4*)(px0 + jj * 4);
    floatx4 x1 = *(const floatx4*)(px1 + jj * 4);
    floatx4 s0v, s1v;
    #pragma unroll
    for (int e = 0; e < 4; e++) {
      float v1 = x0[e] * 0.5f;                       // exact
      float s0 = (v1 >= 1.0f) ? 1.0f : 0.0f;
      float vr = v1 * (1.0f - s0);                   // exact (0 or v1)
      float v2 = vr + (x1[e] - vr) * 0.5f;           // same rounding as reference
      float s1 = (v2 >= 1.0f) ? 1.0f : 0.0f;
      s0v[e] = s0; s1v[e] = s1;
      tile[0][ci][cq * 16 + jj * 4 + e] = s0;
      tile[1][ci][cq * 16 + jj * 4 + e] = s1;
    }
    *(floatx4*)(po0 + jj * 4) = s0v;
    *(floatx4*)(po1 + jj * 4) = s1v;
  }
  __syncthreads();
  const int ni = tid >> 2, cg = tid & 3;   // thread owns row n0+ni, c-word (c0>>4)+cg
  #pragma unroll
  for (int t = 0; t < 2; t++) {
    unsigned int wbits = 0;
    #pragma unroll
    for (int j = 0; j < 16; j++)
      wbits |= (tile[t][cg * 16 + j][ni] != 0.f ? 1u : 0u) << j;
    xb16[((size_t)((t * NB + b) * NN) + n0 + ni) * 16 + (c0 >> 4) + cg] = (unsigned short)wbits;
  }
}

// ---------- kernel 3: fused QKV GEMM + BN + LIF -> fp32 spikes + bit-planes ----------
// A staged via async copy (swizzled slots); B unpacked from xbits (values identical to bf16
// staging — MFMA inputs and accumulation order unchanged => bit-identical results).
__global__ __launch_bounds__(256, 3) void qkv_gemm(
    const unsigned short* __restrict__ xb16,  // [z][n][16 c-words] bit-plane
    const unsigned short* __restrict__ Wsp,   // [3 splits][768][256] bf16
    const float* __restrict__ invv, const float* __restrict__ shv,  // [768]
    float* __restrict__ dq, float* __restrict__ dk, float* __restrict__ dv,
    unsigned short* __restrict__ qbits, unsigned short* __restrict__ kbits,
    unsigned short* __restrict__ vbits)
{
  __shared__ __align__(16) unsigned char smem[33280];
  unsigned short* Al = (unsigned short*)smem;            // 1536 slots (3 splits x 128 rows x 4)
  unsigned short* Bl = (unsigned short*)(smem + 24576);  // 512 slots (2t x 64 rows x 4)
  float* yl = (float*)smem;                              // [128][65] overlaid for exchange
  const int nt = blockIdx.x, mt = blockIdx.y, b = blockIdx.z;
  const int tid = threadIdx.x;
  const int lane = tid & 63, quad = lane >> 4, l16 = lane & 15;
  const int wave = tid >> 6;
  const int tw = wave >> 1, wm = (wave & 1) * 64;        // waves 0,1: t=0 ; waves 2,3: t=1
  floatx4 acc[4][4] = {};
  const int bt = tid >> 7, brow = (tid >> 1) & 63, bhalf = tid & 1;
  const unsigned short* xrow = xb16 + ((size_t)((bt * NB + b) * NN) + nt * 64 + brow) * 16 + bhalf;

  for (int k0 = 0; k0 < 256; k0 += 32) {
    __syncthreads();
    #pragma unroll
    for (int j = 0; j < 6; j++) {            // A: async copy, swizzled slots
      int ci = j * 256 + tid;
      int fr = ci >> 2;
      int kk = (ci & 3) ^ ((fr >> 1) & 3);
      int s = fr >> 7, row = fr & 127;
      const unsigned short* g = Wsp + (size_t)s * 196608 + (size_t)(mt * 128 + row) * 256 + k0 + kk * 8;
      gld_lds16(g, Al + (size_t)ci * 8);
    }
    {                                        // B: unpack 16 bits -> 16 bf16 (2 chunks)
      unsigned int wb = xrow[k0 >> 4];
      uintx4 c0v, c1v;
      #pragma unroll
      for (int p = 0; p < 4; p++) {
        c0v[p] = pk2(((wb >> (2 * p)) & 1) ? 0x3F80 : 0, ((wb >> (2 * p + 1)) & 1) ? 0x3F80 : 0);
        c1v[p] = pk2(((wb >> (8 + 2 * p)) & 1) ? 0x3F80 : 0, ((wb >> (9 + 2 * p)) & 1) ? 0x3F80 : 0);
      }
      int fr = bt * 64 + brow;
      *(uintx4*)(Bl + (size_t)swz(fr, bhalf * 2)     * 8) = c0v;
      *(uintx4*)(Bl + (size_t)swz(fr, bhalf * 2 + 1) * 8) = c1v;
    }
    __syncthreads();

    short8 bfr[4];
    #pragma unroll
    for (int ni = 0; ni < 4; ni++) {
      int fr = tw * 64 + ni * 16 + l16;
      bfr[ni] = *(const short8*)(Bl + (size_t)swz(fr, quad) * 8);
    }
    #pragma unroll
    for (int mi = 0; mi < 4; mi++) {
      const int r0 = wm + mi * 16 + l16;
      short8 a0 = *(const short8*)(Al + (size_t)swz(      r0, quad) * 8);
      short8 a1 = *(const short8*)(Al + (size_t)swz(128 + r0, quad) * 8);
      short8 a2 = *(const short8*)(Al + (size_t)swz(256 + r0, quad) * 8);
      #pragma unroll
      for (int ni = 0; ni < 4; ni++) {
        acc[mi][ni] = __builtin_amdgcn_mfma_f32_16x16x32_bf16(a0, bfr[ni], acc[mi][ni], 0, 0, 0);
        acc[mi][ni] = __builtin_amdgcn_mfma_f32_16x16x32_bf16(a1, bfr[ni], acc[mi][ni], 0, 0, 0);
        acc[mi][ni] = __builtin_amdgcn_mfma_f32_16x16x32_bf16(a2, bfr[ni], acc[mi][ni], 0, 0, 0);
      }
    }
  }
  __syncthreads();                 // staging LDS now dead; reuse as exchange
  if (tw == 0) {                   // t0 waves publish raw accumulators
    #pragma unroll
    for (int mi = 0; mi < 4; mi++)
      #pragma unroll
      for (int r = 0; r < 4; r++)
        #pragma unroll
        for (int ni = 0; ni < 4; ni++)
          yl[(size_t)(wm + mi * 16 + quad * 4 + r) * 65 + ni * 16 + l16] = acc[mi][ni][r];
  }
  __syncthreads();
  if (tw == 1) {                   // t1 waves apply BN + 2-step LIF, write both planes + bits
    #pragma unroll
    for (int mi = 0; mi < 4; mi++) {
      #pragma unroll
      for (int r = 0; r < 4; r++) {
        const int lrow = wm + mi * 16 + quad * 4 + r;
        const int orow = mt * 128 + lrow;
        const float iv = invv[orow], sh = shv[orow];
        const int widx = orow >> 8, c = orow & 255;
        float* dst = (widx == 0) ? dq : (widx == 1) ? dk : dv;
        unsigned short* bb = (widx == 0) ? qbits : (widx == 1) ? kbits : vbits;
        #pragma unroll
        for (int ni = 0; ni < 4; ni++) {
          const int n = nt * 64 + ni * 16 + l16;
          float y0 = yl[(size_t)lrow * 65 + ni * 16 + l16] * iv + sh;
          float y1 = acc[mi][ni][r] * iv + sh;
          float v1 = y0 * 0.5f;
          float s0 = (v1 >= 1.0f) ? 1.0f : 0.0f;
          float vr = v1 * (1.0f - s0);
          float v2 = vr + (y1 - vr) * 0.5f;
          float s1 = (v2 >= 1.0f) ? 1.0f : 0.0f;
          dst[(size_t)(b * NC + c) * NN + n] = s0;
          dst[(size_t)((NB + b) * NC + c) * NN + n] = s1;
          unsigned long long bl0 = __ballot(s0 != 0.0f);   // bit(lane)=quad*16+l16
          unsigned long long bl1 = __ballot(s1 != 0.0f);
          if (l16 == 0) {          // field quad = 16 n-bits of this lane's row c
            const int w16 = nt * 4 + ni;
            bb[(size_t)b        * 65536 + (size_t)c * 256 + w16] = (unsigned short)(bl0 >> (quad * 16));
            bb[(size_t)(NB + b) * 65536 + (size_t)c * 256 + w16] = (unsigned short)(bl1 >> (quad * 16));
          }
        }
      }
    }
  }
}

// ---------- kernel 4: kv = K^T V via popcount over bit-planes (exact integers) ----------
__global__ __launch_bounds__(256) void kv_kernel(const unsigned long long* __restrict__ kb,
                                                 const unsigned long long* __restrict__ vb,
                                                 float* __restrict__ kvout)
{
  __shared__ unsigned long long Kl[32 * 65];   // pitch 65 u64
  __shared__ unsigned long long Vl[32 * 65];
  const int h = blockIdx.x, z = blockIdx.y;    // z = t*16+b
  const int tid = threadIdx.x;
  for (int i = tid; i < 2048; i += 256) {
    int row = i >> 6, w = i & 63;
    size_t g = (size_t)z * 16384 + (size_t)(h * 32 + row) * 64 + w;
    Kl[row * 65 + w] = kb[g];
    Vl[row * 65 + w] = vb[g];
  }
  __syncthreads();
  const int d = tid & 31, e0 = tid >> 5;       // thread: row d x 4 cols (e0+8p)
  int acc0 = 0, acc1 = 0, acc2 = 0, acc3 = 0;
  for (int w = 0; w < 64; w++) {
    unsigned long long ku = Kl[d * 65 + w];
    acc0 += __popcll(ku & Vl[(e0     ) * 65 + w]);
    acc1 += __popcll(ku & Vl[(e0 +  8) * 65 + w]);
    acc2 += __popcll(ku & Vl[(e0 + 16) * 65 + w]);
    acc3 += __popcll(ku & Vl[(e0 + 24) * 65 + w]);
  }
  float* o = kvout + ((size_t)(z * NHD + h) << 10);
  o[d * 32 + e0     ] = (float)acc0;
  o[d * 32 + e0 +  8] = (float)acc1;
  o[d * 32 + e0 + 16] = (float)acc2;
  o[d * 32 + e0 + 24] = (float)acc3;
}

// ---------- kernel 5: attn = 0.125*(q@kv) via exact-integer MFMA, LIF(0.5) -> s bit-plane ----------
__global__ __launch_bounds__(256) void attn_kernel(const unsigned short* __restrict__ qb16,
                                                   const float* __restrict__ kvout,
                                                   unsigned short* __restrict__ sb16)
{
  __shared__ float kvl[2][32][33];
  __shared__ unsigned short qt[2][32][16];    // q bit-words: [t][d][n-word]
  const int nb = blockIdx.x, h = blockIdx.y, b = blockIdx.z;
  const int tid = threadIdx.x;
  const int wave = tid >> 6, lane = tid & 63, quad = lane >> 4, l16 = lane & 15;
  for (int i = tid; i < 2048; i += 256) {
    int t = i >> 10, j = i & 1023;
    kvl[t][j >> 5][j & 31] = kvout[((size_t)((t * NB + b) * NHD + h) << 10) + j];
  }
  for (int i = tid; i < 1024; i += 256) {
    int t = i >> 9, j = i & 511, row = j >> 4, w = j & 15;
    qt[t][row][w] = qb16[(size_t)(t * NB + b) * 65536 + (size_t)(h * 32 + row) * 256 + nb * 16 + w];
  }
  __syncthreads();
  // B-frags: kv split into exact bf16 hi+lo (integers <=4096; |lo|<=8; both exact)
  short8 bf[2][2][2];
  #pragma unroll
  for (int t = 0; t < 2; t++) {
    #pragma unroll
    for (int eh = 0; eh < 2; eh++) {
      short8 bh, bl;
      #pragma unroll
      for (int j = 0; j < 8; j++) {
        float v = kvl[t][quad * 8 + j][eh * 16 + l16];
        unsigned short h0 = f2bf(v);
        float lo = v - bfb2f(h0);
        bh[j] = (short)h0;
        bl[j] = (short)f2bf(lo);
      }
      bf[t][0][eh] = bh; bf[t][1][eh] = bl;
    }
  }
  floatx4 acc[2][4][2] = {};                   // [t][ntile][ehalf]
  #pragma unroll
  for (int t = 0; t < 2; t++) {
    #pragma unroll
    for (int nt = 0; nt < 4; nt++) {
      const int wv = wave * 4 + nt;            // n-word index of this tile
      short8 af;
      #pragma unroll
      for (int j = 0; j < 8; j++) {            // broadcast u16 read + per-lane bit test
        unsigned short w = qt[t][quad * 8 + j][wv];
        af[j] = (short)(((w >> l16) & 1) ? 0x3F80 : 0);
      }
      #pragma unroll
      for (int eh = 0; eh < 2; eh++) {
        acc[t][nt][eh] = __builtin_amdgcn_mfma_f32_16x16x32_bf16(af, bf[t][0][eh], acc[t][nt][eh], 0, 0, 0);
        acc[t][nt][eh] = __builtin_amdgcn_mfma_f32_16x16x32_bf16(af, bf[t][1][eh], acc[t][nt][eh], 0, 0, 0);
      }
    }
  }
  // epilogue: exact dyadic LIF(0.5); pack spikes as bits (16 c per n-row)
  const int n0 = nb * 256 + wave * 64;
  #pragma unroll
  for (int nt = 0; nt < 4; nt++) {
    #pragma unroll
    for (int r = 0; r < 4; r++) {
      const int n = n0 + nt * 16 + quad * 4 + r;          // per-lane (quad)
      #pragma unroll
      for (int eh = 0; eh < 2; eh++) {
        float a0 = acc[0][nt][eh][r] * 0.125f;            // exact dyadic
        float a1 = acc[1][nt][eh][r] * 0.125f;
        float v1 = a0 * 0.5f;
        float s0 = (v1 >= 0.5f) ? 1.f : 0.f;
        float vr = v1 * (1.f - s0);
        float v2 = vr + (a1 - vr) * 0.5f;
        float s1 = (v2 >= 0.5f) ? 1.f : 0.f;
        unsigned long long bl0 = __ballot(s0 != 0.f);     // field quad = 16 c-bits of n(quad)
        unsigned long long bl1 = __ballot(s1 != 0.f);
        if (l16 == 0) {
          const int w16 = h * 2 + eh;
          sb16[(size_t)b        * 65536 + (size_t)n * 16 + w16] = (unsigned short)(bl0 >> (quad * 16));
          sb16[(size_t)(NB + b) * 65536 + (size_t)n * 16 + w16] = (unsigned short)(bl1 >> (quad * 16));
        }
      }
    }
  }
}

// ---------- kernel 6: out = BN(Wp @ s + bp); B unpacked from sbits; swizzled LDS ----------
__global__ __launch_bounds__(256, 3) void p_gemm(
    const unsigned short* __restrict__ sb16,  // [z][n][c-word] bit-plane
    const unsigned short* __restrict__ Wsp,   // [3][256][256]
    const float* __restrict__ invv, const float* __restrict__ shv,
    float* __restrict__ dout)
{
  __shared__ __align__(16) unsigned char smem[32768];
  unsigned short* Al = (unsigned short*)smem;            // 1536 slots
  unsigned short* Bl = (unsigned short*)(smem + 24576);  // 512 slots (128 rows x 4)
  const int nt = blockIdx.x, mt = blockIdx.y, z = blockIdx.z;  // z = t*16+b
  const int tid = threadIdx.x;
  const int lane = tid & 63, quad = lane >> 4, l16 = lane & 15;
  const int wave = tid >> 6;
  const int wm = (wave & 1) * 64, wn = (wave >> 1) * 64;
  floatx4 acc[4][4] = {};
  const int brow = tid & 127, bhalf = tid >> 7;

  for (int k0 = 0; k0 < 256; k0 += 32) {
    __syncthreads();
    #pragma unroll
    for (int j = 0; j < 6; j++) {            // A via async copy, swizzled slots
      int ci = j * 256 + tid;
      int fr = ci >> 2;
      int kk = (ci & 3) ^ ((fr >> 1) & 3);
      int s = fr >> 7, row = fr & 127;
      const unsigned short* g = Wsp + (size_t)s * 65536 + (size_t)(mt * 128 + row) * 256 + k0 + kk * 8;
      gld_lds16(g, Al + (size_t)ci * 8);
    }
    {                                        // B: unpack 16 bits -> 16 bf16 per thread
      unsigned short wb = sb16[(size_t)z * 65536 + (size_t)(nt * 128 + brow) * 16 + (k0 >> 4) + bhalf];
      uintx4 lo4, hi4;
      #pragma unroll
      for (int p = 0; p < 4; p++) {
        lo4[p] = pk2(((wb >> (2 * p)) & 1) ? 0x3F80 : 0, ((wb >> (2 * p + 1)) & 1) ? 0x3F80 : 0);
        hi4[p] = pk2(((wb >> (8 + 2 * p)) & 1) ? 0x3F80 : 0, ((wb >> (9 + 2 * p)) & 1) ? 0x3F80 : 0);
      }
      *(uintx4*)(Bl + (size_t)swz(brow, bhalf * 2)     * 8) = lo4;
      *(uintx4*)(Bl + (size_t)swz(brow, bhalf * 2 + 1) * 8) = hi4;
    }
    __syncthreads();

    short8 bfr[4];
    #pragma unroll
    for (int ni = 0; ni < 4; ni++) {
      int fr = wn + ni * 16 + l16;
      bfr[ni] = *(const short8*)(Bl + (size_t)swz(fr, quad) * 8);
    }
    #pragma unroll
    for (int mi = 0; mi < 4; mi++) {
      const int r0 = wm + mi * 16 + l16;
      short8 a0 = *(const short8*)(Al + (size_t)swz(      r0, quad) * 8);
      short8 a1 = *(const short8*)(Al + (size_t)swz(128 + r0, quad) * 8);
      short8 a2 = *(const short8*)(Al + (size_t)swz(256 + r0, quad) * 8);
      #pragma unroll
      for (int ni = 0; ni < 4; ni++) {
        acc[mi][ni] = __builtin_amdgcn_mfma_f32_16x16x32_bf16(a0, bfr[ni], acc[mi][ni], 0, 0, 0);
        acc[mi][ni] = __builtin_amdgcn_mfma_f32_16x16x32_bf16(a1, bfr[ni], acc[mi][ni], 0, 0, 0);
        acc[mi][ni] = __builtin_amdgcn_mfma_f32_16x16x32_bf16(a2, bfr[ni], acc[mi][ni], 0, 0, 0);
      }
    }
  }
  #pragma unroll
  for (int mi = 0; mi < 4; mi++) {
    #pragma unroll
    for (int r = 0; r < 4; r++) {
      const int orow = mt * 128 + wm + mi * 16 + quad * 4 + r;
      const float iv = invv[orow], sh = shv[orow];
      #pragma unroll
      for (int ni = 0; ni < 4; ni++) {
        const int n = nt * 128 + wn + ni * 16 + l16;
        dout[((size_t)(z * NC + orow)) * NN + n] = acc[mi][ni][r] * iv + sh;
      }
    }
  }
}

// ---------- launch ----------
extern "C" void kernel_launch(void* const* d_in, const int* in_sizes, int n_in,
                              void* d_out, int out_size, void* d_ws, size_t ws_size,
                              hipStream_t stream) {
  (void)in_sizes; (void)n_in; (void)out_size; (void)ws_size;
  const float* x  = (const float*)d_in[0];
  const float* wq = (const float*)d_in[1];
  const float* wk = (const float*)d_in[2];
  const float* wv = (const float*)d_in[3];
  const float* wp = (const float*)d_in[4];
  const float* bp = (const float*)d_in[5];
  const float* qg = (const float*)d_in[6],  *qb = (const float*)d_in[7];
  const float* qm = (const float*)d_in[8],  *qva = (const float*)d_in[9];
  const float* kg = (const float*)d_in[10], *kb = (const float*)d_in[11];
  const float* km = (const float*)d_in[12], *kva = (const float*)d_in[13];
  const float* vg = (const float*)d_in[14], *vb = (const float*)d_in[15];
  const float* vm = (const float*)d_in[16], *vva = (const float*)d_in[17];
  const float* pg = (const float*)d_in[18], *pb = (const float*)d_in[19];
  const float* pm = (const float*)d_in[20], *pva = (const float*)d_in[21];

  float* out = (float*)d_out;       // outputs in return order
  float* xs  = out + NE1;
  float* dq  = out + 2 * NE1;
  float* dk  = out + 3 * NE1;
  float* dv  = out + 4 * NE1;

  char* ws = (char*)d_ws;
  unsigned short* xbits = (unsigned short*)ws;                  // 4194304 B
  unsigned short* Wqkv  = (unsigned short*)(ws + 4194304);      // 1179648 B
  unsigned short* Wp    = (unsigned short*)(ws + 5373952);      // 393216 B
  float* kvout          = (float*)(ws + 5767168);               // 1048576 B
  unsigned short* qbits = (unsigned short*)(ws + 6815744);      // 4194304 B
  unsigned short* kbits = (unsigned short*)(ws + 11010048);     // 4194304 B
  unsigned short* vbits = (unsigned short*)(ws + 15204352);     // 4194304 B
  unsigned short* sbits = (unsigned short*)(ws + 19398656);     // 4194304 B
  float* invqkv         = (float*)(ws + 23592960);              // 768 floats
  float* shqkv          = invqkv + 768;
  float* invp           = shqkv + 768;
  float* shp            = invp + 256;

  prep_kernel<<<1028, 256, 0, stream>>>(wq, wk, wv, wp, bp,
                                        qg, qb, qm, qva, kg, kb, km, kva,
                                        vg, vb, vm, vva, pg, pb, pm, pva,
                                        Wqkv, Wp, invqkv, shqkv, invp, shp);
  lifx_kernel<<<dim3(64, 4, 16), 256, 0, stream>>>(x, xs, xbits);
  qkv_gemm<<<dim3(64, 6, 16), 256, 0, stream>>>(xbits, Wqkv, invqkv, shqkv,
                                                dq, dk, dv, qbits, kbits, vbits);
  kv_kernel<<<dim3(8, 32), 256, 0, stream>>>((const unsigned long long*)kbits,
                                             (const unsigned long long*)vbits, kvout);
  attn_kernel<<<dim3(16, 8, 16), 256, 0, stream>>>(qbits, kvout, sbits);
  p_gemm<<<dim3(32, 2, 32), 256, 0, stream>>>(sbits, Wp, invp, shp, out);
}